// Round 13
// baseline (279.496 us; speedup 1.0000x reference)
//
#include <hip/hip_runtime.h>
#include <hip/hip_bf16.h>

#define N_NODES 6144
#define NQ_ 3072
#define D 128
#define H 4
#define C 32
#define F_IN 10
#define L_LAYERS 4
#define E_EDGES 393216
#define E_TOT (E_EDGES + N_NODES)
#define SPLITS 16
#define KV_PER (N_NODES / SPLITS)  // 384 keys per split = 12 tiles of 32
#define NT_TOT (N_NODES / 32)      // 192 tiles total
#define LOG2E 1.4426950408889634f

typedef __attribute__((ext_vector_type(8))) short bf16x8;
typedef __attribute__((ext_vector_type(4))) float f32x4;
typedef __attribute__((ext_vector_type(16))) float f32x16;

__device__ __forceinline__ unsigned short f2bf(float f) {
  unsigned u = __float_as_uint(f);
  unsigned r = (u + 0x7fffu + ((u >> 16) & 1u)) >> 16;
  return (unsigned short)r;
}

__device__ __forceinline__ float bf2f(unsigned short s) {
  return __uint_as_float(((unsigned)s) << 16);
}

__device__ __forceinline__ unsigned cvtpk(float lo, float hi) {
  unsigned r;
  asm volatile("v_cvt_pk_bf16_f32 %0, %1, %2" : "=v"(r) : "v"(lo), "v"(hi));
  return r;
}

// vdst-high(lanes 32-63) <-> src0-low(lanes 0-31)
#define P32SWAP(a, b) asm volatile("v_permlane32_swap_b32 %0, %1" : "+v"(a), "+v"(b))

#define MFMA32(A, B, CIN) __builtin_amdgcn_mfma_f32_32x32x16_bf16(A, B, CIN, 0, 0, 0)

// ---------- helpers ----------
// dual reduction for 128-thread blocks: a and b summed in one interleaved tree
__device__ __forceinline__ void red128_sum2(float& a, float& b, float* tmp4, int tid) {
#pragma unroll
  for (int m = 1; m < 64; m <<= 1) {
    a += __shfl_xor(a, m, 64);
    b += __shfl_xor(b, m, 64);
  }
  __syncthreads();
  if ((tid & 63) == 0) {
    tmp4[(tid >> 6) * 2]     = a;
    tmp4[(tid >> 6) * 2 + 1] = b;
  }
  __syncthreads();
  a = tmp4[0] + tmp4[2];
  b = tmp4[1] + tmp4[3];
}

// 32x32 output tile of A(rows x 128) @ B^T(cols x 128), both bf16 row-major.
// lane holds D[row=(r&3)+8*(r>>2)+4*hi][col=qc]  (verified fragment map)
__device__ __forceinline__ f32x16 tile_gemm128(const unsigned short* __restrict__ A,
                                               const unsigned short* __restrict__ Bt,
                                               int row0, int col0, int qc, int hi) {
  const unsigned short* ap = A + (size_t)(row0 + qc) * 128 + hi * 8;
  const unsigned short* bp = Bt + (size_t)(col0 + qc) * 128 + hi * 8;
  f32x16 o = {0.f};
#pragma unroll
  for (int kk = 0; kk < 8; kk++) {
    bf16x8 a = *(const bf16x8*)(ap + kk * 16);
    bf16x8 b = *(const bf16x8*)(bp + kk * 16);
    o = MFMA32(a, b, o);
  }
  return o;
}

// ---------- fused prep: zero counters/pooled, GAT W^T, qkv/mlp W^T, pe->bf16 ----------
__global__ void k_prep(int* cnt, int* cur, float* pooled,
                       const float* __restrict__ gatW, unsigned short* __restrict__ wt,
                       const float* __restrict__ Wq, const float* __restrict__ Wk,
                       const float* __restrict__ Wv, const float* __restrict__ W1,
                       const float* __restrict__ W2, const float* __restrict__ Wo,
                       unsigned short* __restrict__ wqt, unsigned short* __restrict__ wkt,
                       unsigned short* __restrict__ wvt, unsigned short* __restrict__ w1t,
                       unsigned short* __restrict__ w2t, unsigned short* __restrict__ wot,
                       const float* __restrict__ pe, unsigned short* __restrict__ pebf) {
  int i = blockIdx.x * 256 + threadIdx.x;
  if (i < 6272) {
    if (i < N_NODES) { cnt[i] = 0; cur[i] = 0; }
    else pooled[i - N_NODES] = 0.f;
    return;
  }
  i -= 6272;
  if (i < 65536) {  // GAT W -> W^T bf16 (4 layers)
    int l = i >> 14, rem = i & 16383, j = rem >> 7, k = rem & 127;
    wt[i] = f2bf(gatW[l * 16384 + k * 128 + j]);
    return;
  }
  i -= 65536;
  if (i < 90112) {  // qkv/mlp weights
    if (i < 65536) {
      int m = i >> 14, loc = i & 16383, j = loc >> 7, k = loc & 127;
      const float* src = (m == 0) ? Wq : (m == 1) ? Wk : (m == 2) ? Wv : W1;
      unsigned short* dst = (m == 0) ? wqt : (m == 1) ? wkt : (m == 2) ? wvt : w1t;
      dst[loc] = f2bf(src[k * 128 + j]);
    } else if (i < 73728) {
      int loc = i - 65536, j = loc >> 7, k = loc & 127;  // j<64
      w2t[loc] = f2bf(W2[k * 64 + j]);
    } else {
      int loc = i - 73728, j = loc >> 7, k = loc & 127;
      wot[loc] = f2bf(Wo[k * 128 + j]);
    }
    return;
  }
  i -= 90112;
  if (i < N_NODES * D / 4) {  // pe -> bf16, float4 granules
    float4 v = ((const float4*)pe)[i];
    unsigned lo = (unsigned)f2bf(v.x) | ((unsigned)f2bf(v.y) << 16);
    unsigned hi = (unsigned)f2bf(v.z) | ((unsigned)f2bf(v.w) << 16);
    *(uint2*)(pebf + (size_t)i * 4) = make_uint2(lo, hi);
  }
}
#define PREP_ITEMS (6272 + 65536 + 90112 + N_NODES * D / 4)

// ---------- CSR build ----------
__global__ void k_hist(const int* __restrict__ dst, int* __restrict__ cnt) {
  for (int i = blockIdx.x * blockDim.x + threadIdx.x; i < E_EDGES; i += gridDim.x * blockDim.x)
    atomicAdd(&cnt[dst[i]], 1);
}

__global__ void k_scan(const int* __restrict__ cnt, int* __restrict__ indptr) {
  __shared__ int ps[256];
  int tid = threadIdx.x;
  const int CH = N_NODES / 256;  // 24
  int base = tid * CH;
  int loc[CH];
  int s = 0;
#pragma unroll
  for (int i = 0; i < CH; i++) { loc[i] = cnt[base + i] + 1; s += loc[i]; }  // +1 self loop
  ps[tid] = s;
  __syncthreads();
  for (int off = 1; off < 256; off <<= 1) {
    int v = (tid >= off) ? ps[tid - off] : 0;
    __syncthreads();
    ps[tid] += v;
    __syncthreads();
  }
  int run = (tid == 0) ? 0 : ps[tid - 1];
#pragma unroll
  for (int i = 0; i < CH; i++) { indptr[base + i] = run; run += loc[i]; }
  if (tid == 255) indptr[N_NODES] = run;
}

__global__ void k_scatter(const int* __restrict__ src, const int* __restrict__ dst,
                          const int* __restrict__ indptr, int* __restrict__ cur,
                          int* __restrict__ sorted) {
  for (int i = blockIdx.x * blockDim.x + threadIdx.x; i < E_TOT; i += gridDim.x * blockDim.x) {
    if (i < E_EDGES) {
      int d = dst[i];
      int p = atomicAdd(&cur[d], 1);
      sorted[indptr[d] + p] = src[i];
    } else {
      int n = i - E_EDGES;
      int p = atomicAdd(&cur[n], 1);
      sorted[indptr[n] + p] = n;
    }
  }
}

// ---------- embedding ----------
__global__ __launch_bounds__(128) void k_embed(const float* __restrict__ nf,
                                               const float* __restrict__ W,
                                               const float* __restrict__ b,
                                               const float* __restrict__ g,
                                               const float* __restrict__ bb,
                                               float* __restrict__ x,
                                               unsigned short* __restrict__ xbf) {
  int n = blockIdx.x, j = threadIdx.x;
  __shared__ float f[F_IN];
  __shared__ float tmp4[4];
  if (j < F_IN) f[j] = nf[n * F_IN + j];
  __syncthreads();
  float acc = b[j];
#pragma unroll
  for (int k = 0; k < F_IN; k++) acc += f[k] * W[k * D + j];
  float s1 = acc, s2 = acc * acc;
  red128_sum2(s1, s2, tmp4, j);
  float mean = s1 * (1.f / D);
  float var = s2 * (1.f / D) - mean * mean;
  float y = (acc - mean) * rsqrtf(var + 1e-5f) * g[j] + bb[j];
  y = fmaxf(y, 0.f);
  x[n * D + j] = y;
  xbf[n * D + j] = f2bf(y);
}

// ---------- GAT: H = X@W via MFMA (bf16 in/out) ----------
__global__ __launch_bounds__(256) void k_gat_gemm(const unsigned short* __restrict__ xbf,
                                                  const unsigned short* __restrict__ wt,
                                                  unsigned short* __restrict__ hbf) {
  int t = threadIdx.x;
  int w = t >> 6, l = t & 63, qc = l & 31, hi = l >> 5;
  int tile = blockIdx.x * 4 + w;           // 768 tiles = (N/32)*(D/32)
  int row0 = (tile >> 2) * 32, col0 = (tile & 3) * 32;
  f32x16 o = tile_gemm128(xbf, wt, row0, col0, qc, hi);
#pragma unroll
  for (int r = 0; r < 16; r++) {
    int rr = (r & 3) + 8 * (r >> 2) + 4 * hi;
    hbf[(size_t)(row0 + rr) * D + col0 + qc] = f2bf(o[r]);
  }
}

// ---------- GAT: a_s, a_d from h (pre-scaled by log2e) ----------
__global__ __launch_bounds__(128) void k_gat_attn(const unsigned short* __restrict__ hbf,
                                                  const float* __restrict__ asrc,
                                                  const float* __restrict__ adst,
                                                  float* __restrict__ a_s,
                                                  float* __restrict__ a_d) {
  int t = threadIdx.x;
  int ni = t >> 4, j = t & 15;
  int n = blockIdx.x * 8 + ni;
  bf16x8 hv = *(const bf16x8*)(hbf + (size_t)n * D + j * 8);
  float4 a0 = *(const float4*)(asrc + j * 8);
  float4 a1 = *(const float4*)(asrc + j * 8 + 4);
  float4 d0 = *(const float4*)(adst + j * 8);
  float4 d1 = *(const float4*)(adst + j * 8 + 4);
  float h0 = bf2f(hv[0]), h1 = bf2f(hv[1]), h2 = bf2f(hv[2]), h3 = bf2f(hv[3]);
  float h4 = bf2f(hv[4]), h5 = bf2f(hv[5]), h6 = bf2f(hv[6]), h7 = bf2f(hv[7]);
  float p = h0 * a0.x + h1 * a0.y + h2 * a0.z + h3 * a0.w +
            h4 * a1.x + h5 * a1.y + h6 * a1.z + h7 * a1.w;
  float q = h0 * d0.x + h1 * d0.y + h2 * d0.z + h3 * d0.w +
            h4 * d1.x + h5 * d1.y + h6 * d1.z + h7 * d1.w;
  p += __shfl_xor(p, 1); p += __shfl_xor(p, 2);
  q += __shfl_xor(q, 1); q += __shfl_xor(q, 2);
  if ((j & 3) == 0) {
    int head = j >> 2;
    a_s[n * H + head] = p * LOG2E;
    a_d[n * H + head] = q * LOG2E;
  }
}

__device__ __forceinline__ float leaky(float v) { return v > 0.f ? v : 0.2f * v; }

// ---------- GAT aggregation: block per node, 2 edges per wave (half-wave per row) ----------
__global__ __launch_bounds__(256) void k_gat_agg(const unsigned short* __restrict__ hbf,
                                                 const float* __restrict__ a_s,
                                                 const float* __restrict__ a_d,
                                                 const int* __restrict__ indptr,
                                                 const int* __restrict__ sorted,
                                                 const float* __restrict__ gb,
                                                 const float* __restrict__ g,
                                                 const float* __restrict__ bb,
                                                 float* __restrict__ x,
                                                 unsigned short* __restrict__ xbf) {
  int n = blockIdx.x, tid = threadIdx.x;
  int wv = tid >> 6, l = tid & 63;
  int half = l >> 5, li = l & 31;
  int beg = indptr[n], end = indptr[n + 1];
  __shared__ int s_src[256];
  __shared__ float s_ex[256 * 4];
  __shared__ float4 red4[4][32];
  __shared__ float rtmp[16];
  __shared__ float tmp8[8];
  float4 ad = *(const float4*)&a_d[n * H];
  int hsel = li >> 3;  // head of channels li*4 .. li*4+3
  const unsigned short* hb = hbf + li * 4;
  float a0 = 0.f, a1 = 0.f, a2 = 0.f, a3 = 0.f, dsum = 0.f;
  float ds0 = 0.f, ds1 = 0.f, ds2 = 0.f, ds3 = 0.f;

  for (int c0 = beg; c0 < end; c0 += 256) {
    __syncthreads();
    int e = c0 + tid;
    if (e < end) {
      int s = sorted[e];
      s_src[tid] = s;
      float4 as = *(const float4*)&a_s[s * H];
      float e0 = exp2f(leaky(as.x + ad.x));
      float e1 = exp2f(leaky(as.y + ad.y));
      float e2 = exp2f(leaky(as.z + ad.z));
      float e3 = exp2f(leaky(as.w + ad.w));
      s_ex[tid * 4 + 0] = e0;
      s_ex[tid * 4 + 1] = e1;
      s_ex[tid * 4 + 2] = e2;
      s_ex[tid * 4 + 3] = e3;
      ds0 += e0; ds1 += e1; ds2 += e2; ds3 += e3;  // for denominator via staging path? no - see below
    }
    __syncthreads();
    int nc = min(256, end - c0);
    int npair = nc >> 1;
    int pi = wv;
    // 8-pair batches (16 edges per wave): 8 independent uint2 gathers in flight
    for (; pi + 28 < npair; pi += 32) {
      int ss[8];
      float aa[8];
#pragma unroll
      for (int u = 0; u < 8; u++) {
        int ee = (pi + u * 4) * 2 + half;
        ss[u] = s_src[ee];
        aa[u] = s_ex[ee * 4 + hsel];
      }
      uint2 dw[8];
#pragma unroll
      for (int u = 0; u < 8; u++) dw[u] = *(const uint2*)(hb + (size_t)ss[u] * D);
#pragma unroll
      for (int u = 0; u < 8; u++) {
        float al = aa[u];
        a0 = fmaf(al, bf2f((unsigned short)(dw[u].x & 0xffff)), a0);
        a1 = fmaf(al, bf2f((unsigned short)(dw[u].x >> 16)), a1);
        a2 = fmaf(al, bf2f((unsigned short)(dw[u].y & 0xffff)), a2);
        a3 = fmaf(al, bf2f((unsigned short)(dw[u].y >> 16)), a3);
        dsum += al;
      }
    }
    for (; pi < npair; pi += 4) {
      int ee = pi * 2 + half;
      int s = s_src[ee];
      float al = s_ex[ee * 4 + hsel];
      uint2 dw = *(const uint2*)(hb + (size_t)s * D);
      a0 = fmaf(al, bf2f((unsigned short)(dw.x & 0xffff)), a0);
      a1 = fmaf(al, bf2f((unsigned short)(dw.x >> 16)), a1);
      a2 = fmaf(al, bf2f((unsigned short)(dw.y & 0xffff)), a2);
      a3 = fmaf(al, bf2f((unsigned short)(dw.y >> 16)), a3);
      dsum += al;
    }
    if (nc & 1) {  // odd tail edge
      int pi2 = nc >> 1;
      if (half == 0 && wv == (pi2 & 3)) {
        int ee = nc - 1;
        int s = s_src[ee];
        float al = s_ex[ee * 4 + hsel];
        uint2 dw = *(const uint2*)(hb + (size_t)s * D);
        a0 = fmaf(al, bf2f((unsigned short)(dw.x & 0xffff)), a0);
        a1 = fmaf(al, bf2f((unsigned short)(dw.x >> 16)), a1);
        a2 = fmaf(al, bf2f((unsigned short)(dw.y & 0xffff)), a2);
        a3 = fmaf(al, bf2f((unsigned short)(dw.y >> 16)), a3);
        dsum += al;
      }
    }
  }
  // combine halves (different edges, same channels)
  a0 += __shfl_xor(a0, 32, 64);
  a1 += __shfl_xor(a1, 32, 64);
  a2 += __shfl_xor(a2, 32, 64);
  a3 += __shfl_xor(a3, 32, 64);
  dsum += __shfl_xor(dsum, 32, 64);
  if (l < 32) red4[wv][li] = make_float4(a0, a1, a2, a3);
  if (l < 32 && (li & 7) == 0) rtmp[wv * 4 + hsel] = dsum;
  __syncthreads();

  float y = 0.f;
  int c = tid;
  if (tid < 128) {
    int g4 = c >> 2, e4 = c & 3;
    float sum = ((const float*)&red4[0][g4])[e4] + ((const float*)&red4[1][g4])[e4] +
                ((const float*)&red4[2][g4])[e4] + ((const float*)&red4[3][g4])[e4];
    int hd = c >> 5;
    float dd = rtmp[hd] + rtmp[4 + hd] + rtmp[8 + hd] + rtmp[12 + hd];
    float outv = sum * (1.f / (dd + 1e-16f)) + gb[c];
    y = x[n * D + c] + fmaxf(outv, 0.f);
  }
  // dual LN reduction across all 4 waves (y=0 for tid>=128)
  float sy = y, syy = y * y;
#pragma unroll
  for (int m = 1; m < 64; m <<= 1) {
    sy += __shfl_xor(sy, m, 64);
    syy += __shfl_xor(syy, m, 64);
  }
  if (l == 0) { tmp8[wv * 2] = sy; tmp8[wv * 2 + 1] = syy; }
  __syncthreads();
  if (tid < 128) {
    float s1 = tmp8[0] + tmp8[2] + tmp8[4] + tmp8[6];
    float s2 = tmp8[1] + tmp8[3] + tmp8[5] + tmp8[7];
    float mean = s1 * (1.f / D);
    float var = s2 * (1.f / D) - mean * mean;
    float o = (y - mean) * rsqrtf(var + 1e-5f) * g[c] + bb[c];
    x[n * D + c] = o;
    xbf[n * D + c] = f2bf(o);
  }
}

// ---------- q/k/v via MFMA -> q row-major bf16 (scaled); K,V packed fragment order ----------
__global__ __launch_bounds__(256) void k_qkv_mfma(const unsigned short* __restrict__ xbf,
                                                  const unsigned short* __restrict__ pebf,
                                                  const unsigned short* __restrict__ wqt,
                                                  const unsigned short* __restrict__ wkt,
                                                  const unsigned short* __restrict__ wvt,
                                                  const float* __restrict__ bq,
                                                  const float* __restrict__ bk,
                                                  const float* __restrict__ bv,
                                                  unsigned short* __restrict__ qbf,
                                                  unsigned short* __restrict__ kpk,
                                                  unsigned short* __restrict__ vpk) {
  int t = threadIdx.x;
  int w = t >> 6, l = t & 63, qc = l & 31, hi = l >> 5;
  int m = blockIdx.y;
  int row0 = blockIdx.x * 32, col0 = w * 32;
  const unsigned short* A = (m == 0) ? xbf : pebf;
  const unsigned short* Bt = (m == 0) ? wqt : (m == 1) ? wkt : wvt;
  f32x16 o = tile_gemm128(A, Bt, row0, col0, qc, hi);
  int c = col0 + qc;
  int hh = col0 >> 5;
  int kt = row0 >> 5;
  if (m == 0) {
    const float sc = 0.25503491f;  // 1/sqrt(32)*log2e
    float bias = bq[c];
#pragma unroll
    for (int r = 0; r < 16; r++) {
      int rr = (r & 3) + 8 * (r >> 2) + 4 * hi;
      qbf[(size_t)(row0 + rr) * D + c] = f2bf((o[r] + bias) * sc);
    }
  } else if (m == 1) {
    float bias = bk[c];
    int kfrag = (qc >> 4) & 1, khi = (qc >> 3) & 1, kj = qc & 7;
    unsigned short* base = kpk + ((((size_t)hh * NT_TOT + kt) * 2 + kfrag) * 64 + khi * 32) * 8 + kj;
#pragma unroll
    for (int r = 0; r < 16; r++) {
      int rr = (r & 3) + 8 * (r >> 2) + 4 * hi;
      base[rr * 8] = f2bf(o[r] + bias);
    }
  } else {
    float bias = bv[c];
#pragma unroll
    for (int r = 0; r < 16; r++) {
      int rr = (r & 3) + 8 * (r >> 2) + 4 * hi;
      int vfrag = (rr >> 4) & 1, vhi = (rr >> 3) & 1, vj = rr & 7;
      vpk[((((size_t)hh * NT_TOT + kt) * 2 + vfrag) * 64 + vhi * 32 + qc) * 8 + vj] =
          f2bf(o[r] + bias);
    }
  }
}

// ---------- flash attention: swapped-operand 32x32 MFMA, no-max softmax, dual acc ----------
#define ALOAD(KA0, KA1, VB0_, VB1_, TI) do { \
  const unsigned short* kp_ = kB + (size_t)(TI) * 1024 + l8; \
  const unsigned short* vp_ = vB + (size_t)(TI) * 1024 + l8; \
  KA0 = *(const bf16x8*)(kp_); \
  KA1 = *(const bf16x8*)(kp_ + 512); \
  VB0_ = *(const bf16x8*)(vp_); \
  VB1_ = *(const bf16x8*)(vp_ + 512); \
} while (0)

#define TILE32(KA0, KA1, VB0_, VB1_, O, LS) do { \
  f32x16 s = MFMA32(KA0, qa0, zz16); \
  s = MFMA32(KA1, qa1, s); \
  float p0 = __builtin_amdgcn_exp2f(s[0]), p1 = __builtin_amdgcn_exp2f(s[1]); \
  float p2 = __builtin_amdgcn_exp2f(s[2]), p3 = __builtin_amdgcn_exp2f(s[3]); \
  float p4 = __builtin_amdgcn_exp2f(s[4]), p5 = __builtin_amdgcn_exp2f(s[5]); \
  float p6 = __builtin_amdgcn_exp2f(s[6]), p7 = __builtin_amdgcn_exp2f(s[7]); \
  float p8 = __builtin_amdgcn_exp2f(s[8]), p9 = __builtin_amdgcn_exp2f(s[9]); \
  float pa = __builtin_amdgcn_exp2f(s[10]), pc = __builtin_amdgcn_exp2f(s[11]); \
  float pd = __builtin_amdgcn_exp2f(s[12]), pe_ = __builtin_amdgcn_exp2f(s[13]); \
  float pf = __builtin_amdgcn_exp2f(s[14]), pg = __builtin_amdgcn_exp2f(s[15]); \
  LS += (((p0 + p1) + (p2 + p3)) + ((p4 + p5) + (p6 + p7))) + \
        (((p8 + p9) + (pa + pc)) + ((pd + pe_) + (pf + pg))); \
  unsigned x0_ = cvtpk(p0, p1), x1_ = cvtpk(p2, p3); \
  unsigned y0_ = cvtpk(p4, p5), y1_ = cvtpk(p6, p7); \
  P32SWAP(x0_, y0_); P32SWAP(x1_, y1_); \
  unsigned x2_ = cvtpk(p8, p9), x3_ = cvtpk(pa, pc); \
  unsigned y2_ = cvtpk(pd, pe_), y3_ = cvtpk(pf, pg); \
  P32SWAP(x2_, y2_); P32SWAP(x3_, y3_); \
  union { unsigned u[4]; bf16x8 v; } fa_, fb_; \
  fa_.u[0] = x0_; fa_.u[1] = x1_; fa_.u[2] = y0_; fa_.u[3] = y1_; \
  fb_.u[0] = x2_; fb_.u[1] = x3_; fb_.u[2] = y2_; fb_.u[3] = y3_; \
  O = MFMA32(VB0_, fa_.v, O); \
  O = MFMA32(VB1_, fb_.v, O); \
} while (0)

__global__ __launch_bounds__(256) void k_attn_split(const unsigned short* __restrict__ qbf,
                                                    const unsigned short* __restrict__ kpk,
                                                    const unsigned short* __restrict__ vpk,
                                                    unsigned short* __restrict__ po,
                                                    float* __restrict__ pl) {
  int hh = blockIdx.y;
  int sp = blockIdx.z;
  int t = threadIdx.x;
  int wid = t >> 6, l = t & 63;
  int qc = l & 31, hi = l >> 5;
  int l8 = l * 8;
  int q0w = blockIdx.x * 128 + wid * 32;

  const f32x16 zz16 = {0.f};

  const unsigned short* qp = qbf + (size_t)(q0w + qc) * D + hh * 32 + hi * 8;
  bf16x8 qa0 = *(const bf16x8*)(qp);
  bf16x8 qa1 = *(const bf16x8*)(qp + 16);

  const unsigned short* kB = kpk + ((size_t)hh * NT_TOT + sp * (KV_PER / 32)) * 1024;
  const unsigned short* vB = vpk + ((size_t)hh * NT_TOT + sp * (KV_PER / 32)) * 1024;

  f32x16 oA = {0.f}, oB = {0.f};
  float lsA = 0.f, lsB = 0.f;

  bf16x8 ka0, ka1, va0, va1, kb0r, kb1r, vb0r, vb1r;
  ALOAD(ka0, ka1, va0, va1, 0);
  const int NT = KV_PER / 32;  // 12 tiles
  for (int it = 0; it < NT; it += 2) {
    ALOAD(kb0r, kb1r, vb0r, vb1r, it + 1);
    TILE32(ka0, ka1, va0, va1, oA, lsA);
    if (it + 2 < NT) ALOAD(ka0, ka1, va0, va1, it + 2);
    TILE32(kb0r, kb1r, vb0r, vb1r, oB, lsB);
  }

  f32x16 o = oA + oB;
  float lsum = lsA + lsB;
  float lt = lsum + __shfl_xor(lsum, 32, 64);
  size_t pbase = (size_t)(sp * H + hh) * N_NODES + q0w + qc;
  unsigned short* pop = po + pbase * 32 + 4 * hi;
  uint2 v0, v1, v2, v3;
  v0.x = cvtpk(o[0], o[1]);   v0.y = cvtpk(o[2], o[3]);
  v1.x = cvtpk(o[4], o[5]);   v1.y = cvtpk(o[6], o[7]);
  v2.x = cvtpk(o[8], o[9]);   v2.y = cvtpk(o[10], o[11]);
  v3.x = cvtpk(o[12], o[13]); v3.y = cvtpk(o[14], o[15]);
  *(uint2*)(pop)      = v0;
  *(uint2*)(pop + 8)  = v1;
  *(uint2*)(pop + 16) = v2;
  *(uint2*)(pop + 24) = v3;
  if (l < 32) {
    pl[pbase] = lt;
  }
}

__global__ __launch_bounds__(256) void k_attn_combine(const unsigned short* __restrict__ po,
                                                      const float* __restrict__ pl,
                                                      unsigned short* __restrict__ xabf) {
  int t = blockIdx.x * 256 + threadIdx.x;  // N*D/2 threads, 2 chans each
  int q = t >> 6, cp = t & 63;
  int c2 = cp * 2, hh = c2 >> 5, c = c2 & 31;
  int base = hh * N_NODES + q;
  const int SN = H * N_NODES;
  float ll = 0.f, olo = 0.f, ohi = 0.f;
#pragma unroll
  for (int s = 0; s < SPLITS; s++) {
    ll += pl[s * SN + base];
    unsigned dw = *(const unsigned*)(po + ((size_t)(s * SN + base)) * 32 + c);
    olo += bf2f((unsigned short)(dw & 0xffff));
    ohi += bf2f((unsigned short)(dw >> 16));
  }
  float inv = 1.f / ll;
  *(unsigned*)(xabf + (size_t)q * D + c2) = cvtpk(olo * inv, ohi * inv);
}

// ---------- Wo GEMM via MFMA ----------
__global__ __launch_bounds__(256) void k_ca_gemm(const unsigned short* __restrict__ xabf,
                                                 const unsigned short* __restrict__ wot,
                                                 const float* __restrict__ bo,
                                                 float* __restrict__ yb) {
  int t = threadIdx.x;
  int w = t >> 6, l = t & 63, qc = l & 31, hi = l >> 5;
  int row0 = blockIdx.x * 32, col0 = w * 32;
  f32x16 o = tile_gemm128(xabf, wot, row0, col0, qc, hi);
  float bias = bo[col0 + qc];
#pragma unroll
  for (int r = 0; r < 16; r++) {
    int rr = (r & 3) + 8 * (r >> 2) + 4 * hi;
    yb[(size_t)(row0 + rr) * D + col0 + qc] = o[r] + bias;
  }
}

// ---------- residual + LN + pooled + outputs ----------
__global__ __launch_bounds__(128) void k_ca_ln(const float* __restrict__ yb,
                                               const float* __restrict__ g,
                                               const float* __restrict__ bb,
                                               float* __restrict__ x,
                                               unsigned short* __restrict__ xbf,
                                               float* __restrict__ pooled,
                                               float* __restrict__ outx) {
  int tid = threadIdx.x, r0 = blockIdx.x * 8;
  __shared__ float tmp4[4];
  float gv = g[tid], bv = bb[tid];
  float psum = 0.f;
#pragma unroll
  for (int r = 0; r < 8; r++) {
    int n = r0 + r;
    float y = x[n * D + tid] + yb[n * D + tid];
    float s1 = y, s2 = y * y;
    red128_sum2(s1, s2, tmp4, tid);
    float mean = s1 * (1.f / D);
    float var = s2 * (1.f / D) - mean * mean;
    float o = (y - mean) * rsqrtf(var + 1e-5f) * gv + bv;
    x[n * D + tid] = o;
    xbf[n * D + tid] = f2bf(o);
    outx[n * D + tid] = o;
    psum += o;
  }
  atomicAdd(&pooled[tid], psum);
}

// ---------- policy head: stage1/stage2 MFMA, stage3 wave-reduce ----------
__global__ __launch_bounds__(256) void k_policy1(const unsigned short* __restrict__ xbf,
                                                 const unsigned short* __restrict__ w1t,
                                                 const float* __restrict__ b1,
                                                 unsigned short* __restrict__ h1) {
  int t = threadIdx.x;
  int w = t >> 6, l = t & 63, qc = l & 31, hi = l >> 5;
  int row0 = blockIdx.x * 32, col0 = w * 32;
  f32x16 o = tile_gemm128(xbf, w1t, row0, col0, qc, hi);
  float bias = b1[col0 + qc];
#pragma unroll
  for (int r = 0; r < 16; r++) {
    int rr = (r & 3) + 8 * (r >> 2) + 4 * hi;
    h1[(size_t)(row0 + rr) * D + col0 + qc] = f2bf(fmaxf(o[r] + bias, 0.f));
  }
}

__global__ __launch_bounds__(128) void k_policy2(const unsigned short* __restrict__ h1,
                                                 const unsigned short* __restrict__ w2t,
                                                 const float* __restrict__ b2,
                                                 unsigned short* __restrict__ h2) {
  int t = threadIdx.x;
  int w = t >> 6, l = t & 63, qc = l & 31, hi = l >> 5;
  int row0 = blockIdx.x * 32, col0 = w * 32;
  f32x16 o = tile_gemm128(h1, w2t, row0, col0, qc, hi);
  float bias = b2[col0 + qc];
#pragma unroll
  for (int r = 0; r < 16; r++) {
    int rr = (r & 3) + 8 * (r >> 2) + 4 * hi;
    h2[(size_t)(row0 + rr) * 64 + col0 + qc] = f2bf(fmaxf(o[r] + bias, 0.f));
  }
}

__global__ __launch_bounds__(256) void k_policy3(const unsigned short* __restrict__ h2,
                                                 const float* __restrict__ W3,
                                                 const float* __restrict__ b3,
                                                 float* __restrict__ logits) {
  int t = threadIdx.x;
  int wv = t >> 6, l = t & 63;
  int n = blockIdx.x * 4 + wv;
  float h = bf2f(h2[(size_t)n * 64 + l]);
  float p0 = h * W3[l * 2];
  float p1 = h * W3[l * 2 + 1];
#pragma unroll
  for (int m = 1; m < 64; m <<= 1) { p0 += __shfl_xor(p0, m, 64); p1 += __shfl_xor(p1, m, 64); }
  if (l == 0) {
    logits[n * 2] = p0 + b3[0];
    logits[n * 2 + 1] = p1 + b3[1];
  }
}

// ---------- value head (single block) ----------
__global__ __launch_bounds__(128) void k_value(const float* __restrict__ pooled,
                                               const float* __restrict__ W1,
                                               const float* __restrict__ b1,
                                               const float* __restrict__ W2,
                                               const float* __restrict__ b2,
                                               const float* __restrict__ W3,
                                               const float* __restrict__ b3,
                                               float* __restrict__ val) {
  int tid = threadIdx.x;
  __shared__ float ps[D], v1[D], v2[64];
  ps[tid] = pooled[tid] * (1.f / N_NODES);
  __syncthreads();
  float a = b1[tid];
  for (int kk = 0; kk < D; kk++) a += ps[kk] * W1[kk * D + tid];
  v1[tid] = fmaxf(a, 0.f);
  __syncthreads();
  if (tid < 64) {
    float a2 = b2[tid];
    for (int kk = 0; kk < D; kk++) a2 += v1[kk] * W2[kk * 64 + tid];
    v2[tid] = fmaxf(a2, 0.f);
  }
  __syncthreads();
  float p = (tid < 64) ? v2[tid] * W3[tid] : 0.f;
#pragma unroll
  for (int m = 1; m < 64; m <<= 1) p += __shfl_xor(p, m, 64);
  if (tid == 0) val[0] = p + b3[0];
}

extern "C" void kernel_launch(void* const* d_in, const int* in_sizes, int n_in,
                              void* d_out, int out_size, void* d_ws, size_t ws_size,
                              hipStream_t stream) {
  const float* nf   = (const float*)d_in[0];
  const int*   ei   = (const int*)d_in[1];
  const float* pe   = (const float*)d_in[2];
  const float* embW = (const float*)d_in[3];
  const float* embB = (const float*)d_in[4];
  const float* elng = (const float*)d_in[5];
  const float* elnb = (const float*)d_in[6];
  const float* gatW = (const float*)d_in[7];
  const float* aS   = (const float*)d_in[8];
  const float* aD   = (const float*)d_in[9];
  const float* gatB = (const float*)d_in[10];
  const float* lng  = (const float*)d_in[11];
  const float* lnb  = (const float*)d_in[12];
  const float* Wq   = (const float*)d_in[13];
  const float* Wk   = (const float*)d_in[14];
  const float* Wv   = (const float*)d_in[15];
  const float* Wo   = (const float*)d_in[16];
  const float* bq   = (const float*)d_in[17];
  const float* bk   = (const float*)d_in[18];
  const float* bv   = (const float*)d_in[19];
  const float* bo   = (const float*)d_in[20];
  const float* cag  = (const float*)d_in[21];
  const float* cab  = (const float*)d_in[22];
  const float* pW1  = (const float*)d_in[23];
  const float* pb1  = (const float*)d_in[24];
  const float* pW2  = (const float*)d_in[25];
  const float* pb2  = (const float*)d_in[26];
  const float* pW3  = (const float*)d_in[27];
  const float* pb3  = (const float*)d_in[28];
  const float* vW1  = (const float*)d_in[29];
  const float* vb1  = (const float*)d_in[30];
  const float* vW2  = (const float*)d_in[31];
  const float* vb2  = (const float*)d_in[32];
  const float* vW3  = (const float*)d_in[33];
  const float* vb3  = (const float*)d_in[34];

  // workspace layout
  float* fw = (float*)d_ws;
  float* x      = fw; fw += N_NODES * D;
  float* hbuf   = fw; fw += N_NODES * D;   // bf16 h during GAT; fp32 yb for ca
  float* a_s    = fw; fw += N_NODES * H;
  float* a_d    = fw; fw += N_NODES * H;
  float* pooled = fw; fw += 128;
  float* pl     = fw; fw += SPLITS * H * N_NODES;
  unsigned short* ub = (unsigned short*)fw;
  unsigned short* po   = ub; ub += (size_t)SPLITS * H * N_NODES * 32;
  unsigned short* qbf  = ub; ub += N_NODES * D;   // reused as h1/h2 after attention
  unsigned short* kpk  = ub; ub += N_NODES * D;   // reused as xabf after attention
  unsigned short* vpk  = ub; ub += N_NODES * D;
  unsigned short* xbf  = ub; ub += N_NODES * D;
  unsigned short* pebf = ub; ub += N_NODES * D;
  unsigned short* wtb  = ub; ub += L_LAYERS * D * D;
  unsigned short* wqt  = ub; ub += D * D;
  unsigned short* wkt  = ub; ub += D * D;
  unsigned short* wvt  = ub; ub += D * D;
  unsigned short* w1t  = ub; ub += D * D;
  unsigned short* w2t  = ub; ub += 64 * D;
  unsigned short* wot  = ub; ub += D * D;
  int* ib     = (int*)ub;
  int* cnt    = ib; ib += N_NODES;
  int* cur    = ib; ib += N_NODES;
  int* indptr = ib; ib += N_NODES + 16;
  int* sorted = ib;

  unsigned short* hbf  = (unsigned short*)hbuf;  // bf16 alias during GAT
  float* yb            = hbuf;                   // fp32 alias for ca gemm out
  unsigned short* xabf = kpk;                    // kpk free after attn_split
  unsigned short* h1   = qbf;                    // qbf free after attn_split
  unsigned short* h2   = qbf + (size_t)NQ_ * D;

  float* out    = (float*)d_out;
  float* logits = out;
  float* val    = out + NQ_ * 2;
  float* outx   = out + NQ_ * 2 + 1;

  const int* esrc = ei;
  const int* edst = ei + E_EDGES;

  hipLaunchKernelGGL(k_prep, dim3((PREP_ITEMS + 255) / 256), dim3(256), 0, stream,
                     cnt, cur, pooled, gatW, wtb, Wq, Wk, Wv, pW1, pW2, Wo,
                     wqt, wkt, wvt, w1t, w2t, wot, pe, pebf);
  hipLaunchKernelGGL(k_hist, dim3(512), dim3(256), 0, stream, edst, cnt);
  hipLaunchKernelGGL(k_scan, dim3(1), dim3(256), 0, stream, cnt, indptr);
  hipLaunchKernelGGL(k_scatter, dim3(512), dim3(256), 0, stream, esrc, edst, indptr, cur, sorted);
  hipLaunchKernelGGL(k_embed, dim3(N_NODES), dim3(128), 0, stream, nf, embW, embB, elng, elnb, x, xbf);
  for (int l = 0; l < L_LAYERS; l++) {
    hipLaunchKernelGGL(k_gat_gemm, dim3(N_NODES / 32), dim3(256), 0, stream,
                       xbf, wtb + l * D * D, hbf);
    hipLaunchKernelGGL(k_gat_attn, dim3(N_NODES / 8), dim3(128), 0, stream,
                       hbf, aS + l * D, aD + l * D, a_s, a_d);
    hipLaunchKernelGGL(k_gat_agg, dim3(N_NODES), dim3(256), 0, stream,
                       hbf, a_s, a_d, indptr, sorted, gatB + l * D, lng + l * D, lnb + l * D, x, xbf);
  }
  hipLaunchKernelGGL(k_qkv_mfma, dim3(N_NODES / 32, 3), dim3(256), 0, stream,
                     xbf, pebf, wqt, wkt, wvt, bq, bk, bv, qbf, kpk, vpk);
  hipLaunchKernelGGL(k_attn_split, dim3(N_NODES / 128, H, SPLITS), dim3(256), 0, stream,
                     qbf, kpk, vpk, po, pl);
  hipLaunchKernelGGL(k_attn_combine, dim3(N_NODES * D / 512), dim3(256), 0, stream,
                     po, pl, xabf);
  hipLaunchKernelGGL(k_ca_gemm, dim3(N_NODES / 32), dim3(256), 0, stream, xabf, wot, bo, yb);
  hipLaunchKernelGGL(k_ca_ln, dim3(N_NODES / 8), dim3(128), 0, stream,
                     yb, cag, cab, x, xbf, pooled, outx);
  hipLaunchKernelGGL(k_policy1, dim3(NQ_ / 32), dim3(256), 0, stream, xbf, w1t, pb1, h1);
  hipLaunchKernelGGL(k_policy2, dim3(NQ_ / 32), dim3(128), 0, stream, h1, w2t, pb2, h2);
  hipLaunchKernelGGL(k_policy3, dim3(NQ_ / 4), dim3(256), 0, stream, h2, pW3, pb3, logits);
  hipLaunchKernelGGL(k_value, dim3(1), dim3(128), 0, stream,
                     pooled, vW1, vb1, vW2, vb2, vW3, vb3, val);
}

// Round 14
// 268.444 us; speedup vs baseline: 1.0412x; 1.0412x over previous
//
#include <hip/hip_runtime.h>
#include <hip/hip_bf16.h>

#define N_NODES 6144
#define NQ_ 3072
#define D 128
#define H 4
#define C 32
#define F_IN 10
#define L_LAYERS 4
#define E_EDGES 393216
#define E_TOT (E_EDGES + N_NODES)
#define SPLITS 8
#define KV_PER (N_NODES / SPLITS)  // 768 keys per split = 24 tiles of 32
#define NT_TOT (N_NODES / 32)      // 192 tiles total
#define LOG2E 1.4426950408889634f

typedef __attribute__((ext_vector_type(8))) short bf16x8;
typedef __attribute__((ext_vector_type(4))) float f32x4;
typedef __attribute__((ext_vector_type(16))) float f32x16;

__device__ __forceinline__ unsigned short f2bf(float f) {
  unsigned u = __float_as_uint(f);
  unsigned r = (u + 0x7fffu + ((u >> 16) & 1u)) >> 16;
  return (unsigned short)r;
}

__device__ __forceinline__ float bf2f(unsigned short s) {
  return __uint_as_float(((unsigned)s) << 16);
}

__device__ __forceinline__ unsigned cvtpk(float lo, float hi) {
  unsigned r;
  asm volatile("v_cvt_pk_bf16_f32 %0, %1, %2" : "=v"(r) : "v"(lo), "v"(hi));
  return r;
}

// vdst-high(lanes 32-63) <-> src0-low(lanes 0-31)
#define P32SWAP(a, b) asm volatile("v_permlane32_swap_b32 %0, %1" : "+v"(a), "+v"(b))

#define MFMA32(A, B, CIN) __builtin_amdgcn_mfma_f32_32x32x16_bf16(A, B, CIN, 0, 0, 0)

// ---------- helpers ----------
// dual reduction for 128-thread blocks: a and b summed in one interleaved tree
__device__ __forceinline__ void red128_sum2(float& a, float& b, float* tmp4, int tid) {
#pragma unroll
  for (int m = 1; m < 64; m <<= 1) {
    a += __shfl_xor(a, m, 64);
    b += __shfl_xor(b, m, 64);
  }
  __syncthreads();
  if ((tid & 63) == 0) {
    tmp4[(tid >> 6) * 2]     = a;
    tmp4[(tid >> 6) * 2 + 1] = b;
  }
  __syncthreads();
  a = tmp4[0] + tmp4[2];
  b = tmp4[1] + tmp4[3];
}

// 32x32 output tile of A(rows x 128) @ B^T(cols x 128), both bf16 row-major.
// lane holds D[row=(r&3)+8*(r>>2)+4*hi][col=qc]  (verified fragment map)
__device__ __forceinline__ f32x16 tile_gemm128(const unsigned short* __restrict__ A,
                                               const unsigned short* __restrict__ Bt,
                                               int row0, int col0, int qc, int hi) {
  const unsigned short* ap = A + (size_t)(row0 + qc) * 128 + hi * 8;
  const unsigned short* bp = Bt + (size_t)(col0 + qc) * 128 + hi * 8;
  f32x16 o = {0.f};
#pragma unroll
  for (int kk = 0; kk < 8; kk++) {
    bf16x8 a = *(const bf16x8*)(ap + kk * 16);
    bf16x8 b = *(const bf16x8*)(bp + kk * 16);
    o = MFMA32(a, b, o);
  }
  return o;
}

// ---------- fused prep: zero counters/pooled, GAT W^T, qkv/mlp W^T, pe->bf16 ----------
__global__ void k_prep(int* cnt, int* cur, float* pooled,
                       const float* __restrict__ gatW, unsigned short* __restrict__ wt,
                       const float* __restrict__ Wq, const float* __restrict__ Wk,
                       const float* __restrict__ Wv, const float* __restrict__ W1,
                       const float* __restrict__ W2, const float* __restrict__ Wo,
                       unsigned short* __restrict__ wqt, unsigned short* __restrict__ wkt,
                       unsigned short* __restrict__ wvt, unsigned short* __restrict__ w1t,
                       unsigned short* __restrict__ w2t, unsigned short* __restrict__ wot,
                       const float* __restrict__ pe, unsigned short* __restrict__ pebf) {
  int i = blockIdx.x * 256 + threadIdx.x;
  if (i < 6272) {
    if (i < N_NODES) { cnt[i] = 0; cur[i] = 0; }
    else pooled[i - N_NODES] = 0.f;
    return;
  }
  i -= 6272;
  if (i < 65536) {  // GAT W -> W^T bf16 (4 layers)
    int l = i >> 14, rem = i & 16383, j = rem >> 7, k = rem & 127;
    wt[i] = f2bf(gatW[l * 16384 + k * 128 + j]);
    return;
  }
  i -= 65536;
  if (i < 90112) {  // qkv/mlp weights
    if (i < 65536) {
      int m = i >> 14, loc = i & 16383, j = loc >> 7, k = loc & 127;
      const float* src = (m == 0) ? Wq : (m == 1) ? Wk : (m == 2) ? Wv : W1;
      unsigned short* dst = (m == 0) ? wqt : (m == 1) ? wkt : (m == 2) ? wvt : w1t;
      dst[loc] = f2bf(src[k * 128 + j]);
    } else if (i < 73728) {
      int loc = i - 65536, j = loc >> 7, k = loc & 127;  // j<64
      w2t[loc] = f2bf(W2[k * 64 + j]);
    } else {
      int loc = i - 73728, j = loc >> 7, k = loc & 127;
      wot[loc] = f2bf(Wo[k * 128 + j]);
    }
    return;
  }
  i -= 90112;
  if (i < N_NODES * D / 4) {  // pe -> bf16, float4 granules
    float4 v = ((const float4*)pe)[i];
    unsigned lo = (unsigned)f2bf(v.x) | ((unsigned)f2bf(v.y) << 16);
    unsigned hi = (unsigned)f2bf(v.z) | ((unsigned)f2bf(v.w) << 16);
    *(uint2*)(pebf + (size_t)i * 4) = make_uint2(lo, hi);
  }
}
#define PREP_ITEMS (6272 + 65536 + 90112 + N_NODES * D / 4)

// ---------- CSR build ----------
__global__ void k_hist(const int* __restrict__ dst, int* __restrict__ cnt) {
  for (int i = blockIdx.x * blockDim.x + threadIdx.x; i < E_EDGES; i += gridDim.x * blockDim.x)
    atomicAdd(&cnt[dst[i]], 1);
}

__global__ void k_scan(const int* __restrict__ cnt, int* __restrict__ indptr) {
  __shared__ int ps[256];
  int tid = threadIdx.x;
  const int CH = N_NODES / 256;  // 24
  int base = tid * CH;
  int loc[CH];
  int s = 0;
#pragma unroll
  for (int i = 0; i < CH; i++) { loc[i] = cnt[base + i] + 1; s += loc[i]; }  // +1 self loop
  ps[tid] = s;
  __syncthreads();
  for (int off = 1; off < 256; off <<= 1) {
    int v = (tid >= off) ? ps[tid - off] : 0;
    __syncthreads();
    ps[tid] += v;
    __syncthreads();
  }
  int run = (tid == 0) ? 0 : ps[tid - 1];
#pragma unroll
  for (int i = 0; i < CH; i++) { indptr[base + i] = run; run += loc[i]; }
  if (tid == 255) indptr[N_NODES] = run;
}

__global__ void k_scatter(const int* __restrict__ src, const int* __restrict__ dst,
                          const int* __restrict__ indptr, int* __restrict__ cur,
                          int* __restrict__ sorted) {
  for (int i = blockIdx.x * blockDim.x + threadIdx.x; i < E_TOT; i += gridDim.x * blockDim.x) {
    if (i < E_EDGES) {
      int d = dst[i];
      int p = atomicAdd(&cur[d], 1);
      sorted[indptr[d] + p] = src[i];
    } else {
      int n = i - E_EDGES;
      int p = atomicAdd(&cur[n], 1);
      sorted[indptr[n] + p] = n;
    }
  }
}

// ---------- embedding ----------
__global__ __launch_bounds__(128) void k_embed(const float* __restrict__ nf,
                                               const float* __restrict__ W,
                                               const float* __restrict__ b,
                                               const float* __restrict__ g,
                                               const float* __restrict__ bb,
                                               float* __restrict__ x,
                                               unsigned short* __restrict__ xbf) {
  int n = blockIdx.x, j = threadIdx.x;
  __shared__ float f[F_IN];
  __shared__ float tmp4[4];
  if (j < F_IN) f[j] = nf[n * F_IN + j];
  __syncthreads();
  float acc = b[j];
#pragma unroll
  for (int k = 0; k < F_IN; k++) acc += f[k] * W[k * D + j];
  float s1 = acc, s2 = acc * acc;
  red128_sum2(s1, s2, tmp4, j);
  float mean = s1 * (1.f / D);
  float var = s2 * (1.f / D) - mean * mean;
  float y = (acc - mean) * rsqrtf(var + 1e-5f) * g[j] + bb[j];
  y = fmaxf(y, 0.f);
  x[n * D + j] = y;
  xbf[n * D + j] = f2bf(y);
}

// ---------- GAT: H = X@W via MFMA + fused a_s/a_d (wave w = head w) ----------
__global__ __launch_bounds__(256) void k_gat_gemm(const unsigned short* __restrict__ xbf,
                                                  const unsigned short* __restrict__ wt,
                                                  const float* __restrict__ asrc,
                                                  const float* __restrict__ adst,
                                                  unsigned short* __restrict__ hbf,
                                                  float* __restrict__ a_s,
                                                  float* __restrict__ a_d) {
  int t = threadIdx.x;
  int w = t >> 6, l = t & 63, qc = l & 31, hi = l >> 5;
  int row0 = blockIdx.x * 32, col0 = w * 32;
  f32x16 o = tile_gemm128(xbf, wt, row0, col0, qc, hi);
#pragma unroll
  for (int r = 0; r < 16; r++) {
    int rr = (r & 3) + 8 * (r >> 2) + 4 * hi;
    hbf[(size_t)(row0 + rr) * D + col0 + qc] = f2bf(o[r]);
  }
  // fused attention coefficients: wave w covers channels of head w for these 32 rows
  float av = asrc[col0 + qc];
  float dv = adst[col0 + qc];
#pragma unroll
  for (int r = 0; r < 16; r++) {
    float pS = o[r] * av;
    float pD = o[r] * dv;
#pragma unroll
    for (int m = 1; m < 32; m <<= 1) {
      pS += __shfl_xor(pS, m, 64);
      pD += __shfl_xor(pD, m, 64);
    }
    if (qc == 0) {
      int rr = (r & 3) + 8 * (r >> 2) + 4 * hi;
      a_s[(row0 + rr) * H + w] = pS * LOG2E;
      a_d[(row0 + rr) * H + w] = pD * LOG2E;
    }
  }
}

__device__ __forceinline__ float leaky(float v) { return v > 0.f ? v : 0.2f * v; }

// ---------- GAT aggregation: block per node, staged ex/src, 8-deep gather batches ----------
__global__ __launch_bounds__(256) void k_gat_agg(const unsigned short* __restrict__ hbf,
                                                 const float* __restrict__ a_s,
                                                 const float* __restrict__ a_d,
                                                 const int* __restrict__ indptr,
                                                 const int* __restrict__ sorted,
                                                 const float* __restrict__ gb,
                                                 const float* __restrict__ g,
                                                 const float* __restrict__ bb,
                                                 float* __restrict__ x,
                                                 unsigned short* __restrict__ xbf) {
  int n = blockIdx.x, tid = threadIdx.x;
  int wv = tid >> 6, l = tid & 63;
  int beg = indptr[n], end = indptr[n + 1];
  __shared__ int s_src[256];
  __shared__ float s_ex[256 * 4];
  __shared__ float2 red2[4][64];
  __shared__ float rtmp[16];
  __shared__ float tmp8[8];
  float4 ad = *(const float4*)&a_d[n * H];
  int hsel = l >> 4;  // head of channels 2l, 2l+1
  const unsigned short* hb = hbf + l * 2;
  float accx = 0.f, accy = 0.f;
  float d0 = 0.f, d1 = 0.f, d2 = 0.f, d3 = 0.f;

  for (int c0 = beg; c0 < end; c0 += 256) {
    __syncthreads();
    int e = c0 + tid;
    if (e < end) {
      int s = sorted[e];
      s_src[tid] = s;
      float4 as = *(const float4*)&a_s[s * H];
      float e0 = exp2f(leaky(as.x + ad.x));
      float e1 = exp2f(leaky(as.y + ad.y));
      float e2 = exp2f(leaky(as.z + ad.z));
      float e3 = exp2f(leaky(as.w + ad.w));
      s_ex[tid * 4 + 0] = e0;
      s_ex[tid * 4 + 1] = e1;
      s_ex[tid * 4 + 2] = e2;
      s_ex[tid * 4 + 3] = e3;
      d0 += e0; d1 += e1; d2 += e2; d3 += e3;
    }
    __syncthreads();
    int nc = min(256, end - c0);
    int i = wv;
    // 8-deep batches: 8 independent gathers in flight per wave
    for (; i + 28 < nc; i += 32) {
      int ss[8];
      float aa[8];
#pragma unroll
      for (int u = 0; u < 8; u++) {
        int idx = i + u * 4;
        ss[u] = s_src[idx];
        aa[u] = s_ex[idx * 4 + hsel];
      }
      unsigned dw[8];
#pragma unroll
      for (int u = 0; u < 8; u++) dw[u] = *(const unsigned*)(hb + (size_t)ss[u] * D);
#pragma unroll
      for (int u = 0; u < 8; u++) {
        accx = fmaf(aa[u], bf2f((unsigned short)(dw[u] & 0xffff)), accx);
        accy = fmaf(aa[u], bf2f((unsigned short)(dw[u] >> 16)), accy);
      }
    }
    for (; i < nc; i += 4) {
      float al = s_ex[i * 4 + hsel];
      int s = s_src[i];
      unsigned dw = *(const unsigned*)(hb + (size_t)s * D);
      accx = fmaf(al, bf2f((unsigned short)(dw & 0xffff)), accx);
      accy = fmaf(al, bf2f((unsigned short)(dw >> 16)), accy);
    }
  }
  red2[wv][l] = make_float2(accx, accy);
  // reduce 4 denominators in one interleaved wave tree
#pragma unroll
  for (int m = 1; m < 64; m <<= 1) {
    d0 += __shfl_xor(d0, m, 64);
    d1 += __shfl_xor(d1, m, 64);
    d2 += __shfl_xor(d2, m, 64);
    d3 += __shfl_xor(d3, m, 64);
  }
  if (l == 0) {
    rtmp[wv * 4 + 0] = d0; rtmp[wv * 4 + 1] = d1;
    rtmp[wv * 4 + 2] = d2; rtmp[wv * 4 + 3] = d3;
  }
  __syncthreads();

  float y = 0.f;
  int c = tid;
  if (tid < 128) {
    const float* rp0 = (const float*)&red2[0][c >> 1];
    const float* rp1 = (const float*)&red2[1][c >> 1];
    const float* rp2 = (const float*)&red2[2][c >> 1];
    const float* rp3 = (const float*)&red2[3][c >> 1];
    int par = c & 1;
    float sum = rp0[par] + rp1[par] + rp2[par] + rp3[par];
    int hd = c >> 5;
    float dd = rtmp[hd] + rtmp[4 + hd] + rtmp[8 + hd] + rtmp[12 + hd];
    float outv = sum * (1.f / (dd + 1e-16f)) + gb[c];
    y = x[n * D + c] + fmaxf(outv, 0.f);
  }
  // dual LN reduction across all 4 waves (y=0 for tid>=128)
  float sy = y, syy = y * y;
#pragma unroll
  for (int m = 1; m < 64; m <<= 1) {
    sy += __shfl_xor(sy, m, 64);
    syy += __shfl_xor(syy, m, 64);
  }
  if (l == 0) { tmp8[wv * 2] = sy; tmp8[wv * 2 + 1] = syy; }
  __syncthreads();
  if (tid < 128) {
    float s1 = tmp8[0] + tmp8[2] + tmp8[4] + tmp8[6];
    float s2 = tmp8[1] + tmp8[3] + tmp8[5] + tmp8[7];
    float mean = s1 * (1.f / D);
    float var = s2 * (1.f / D) - mean * mean;
    float o = (y - mean) * rsqrtf(var + 1e-5f) * g[c] + bb[c];
    x[n * D + c] = o;
    xbf[n * D + c] = f2bf(o);
  }
}

// ---------- q/k/v via MFMA -> q row-major bf16 (scaled); K,V packed fragment order ----------
__global__ __launch_bounds__(256) void k_qkv_mfma(const unsigned short* __restrict__ xbf,
                                                  const unsigned short* __restrict__ pebf,
                                                  const unsigned short* __restrict__ wqt,
                                                  const unsigned short* __restrict__ wkt,
                                                  const unsigned short* __restrict__ wvt,
                                                  const float* __restrict__ bq,
                                                  const float* __restrict__ bk,
                                                  const float* __restrict__ bv,
                                                  unsigned short* __restrict__ qbf,
                                                  unsigned short* __restrict__ kpk,
                                                  unsigned short* __restrict__ vpk) {
  int t = threadIdx.x;
  int w = t >> 6, l = t & 63, qc = l & 31, hi = l >> 5;
  int m = blockIdx.y;
  int row0 = blockIdx.x * 32, col0 = w * 32;
  const unsigned short* A = (m == 0) ? xbf : pebf;
  const unsigned short* Bt = (m == 0) ? wqt : (m == 1) ? wkt : wvt;
  f32x16 o = tile_gemm128(A, Bt, row0, col0, qc, hi);
  int c = col0 + qc;
  int hh = col0 >> 5;
  int kt = row0 >> 5;
  if (m == 0) {
    const float sc = 0.25503491f;  // 1/sqrt(32)*log2e
    float bias = bq[c];
#pragma unroll
    for (int r = 0; r < 16; r++) {
      int rr = (r & 3) + 8 * (r >> 2) + 4 * hi;
      qbf[(size_t)(row0 + rr) * D + c] = f2bf((o[r] + bias) * sc);
    }
  } else if (m == 1) {
    float bias = bk[c];
    int kfrag = (qc >> 4) & 1, khi = (qc >> 3) & 1, kj = qc & 7;
    unsigned short* base = kpk + ((((size_t)hh * NT_TOT + kt) * 2 + kfrag) * 64 + khi * 32) * 8 + kj;
#pragma unroll
    for (int r = 0; r < 16; r++) {
      int rr = (r & 3) + 8 * (r >> 2) + 4 * hi;
      base[rr * 8] = f2bf(o[r] + bias);
    }
  } else {
    float bias = bv[c];
#pragma unroll
    for (int r = 0; r < 16; r++) {
      int rr = (r & 3) + 8 * (r >> 2) + 4 * hi;
      int vfrag = (rr >> 4) & 1, vhi = (rr >> 3) & 1, vj = rr & 7;
      vpk[((((size_t)hh * NT_TOT + kt) * 2 + vfrag) * 64 + vhi * 32 + qc) * 8 + vj] =
          f2bf(o[r] + bias);
    }
  }
}

// ---------- flash attention: swapped-operand 32x32 MFMA, no-max softmax, dual acc ----------
#define ALOAD(KA0, KA1, VB0_, VB1_, TI) do { \
  const unsigned short* kp_ = kB + (size_t)(TI) * 1024 + l8; \
  const unsigned short* vp_ = vB + (size_t)(TI) * 1024 + l8; \
  KA0 = *(const bf16x8*)(kp_); \
  KA1 = *(const bf16x8*)(kp_ + 512); \
  VB0_ = *(const bf16x8*)(vp_); \
  VB1_ = *(const bf16x8*)(vp_ + 512); \
} while (0)

#define TILE32(KA0, KA1, VB0_, VB1_, O, LS) do { \
  f32x16 s = MFMA32(KA0, qa0, zz16); \
  s = MFMA32(KA1, qa1, s); \
  float p0 = __builtin_amdgcn_exp2f(s[0]), p1 = __builtin_amdgcn_exp2f(s[1]); \
  float p2 = __builtin_amdgcn_exp2f(s[2]), p3 = __builtin_amdgcn_exp2f(s[3]); \
  float p4 = __builtin_amdgcn_exp2f(s[4]), p5 = __builtin_amdgcn_exp2f(s[5]); \
  float p6 = __builtin_amdgcn_exp2f(s[6]), p7 = __builtin_amdgcn_exp2f(s[7]); \
  float p8 = __builtin_amdgcn_exp2f(s[8]), p9 = __builtin_amdgcn_exp2f(s[9]); \
  float pa = __builtin_amdgcn_exp2f(s[10]), pc = __builtin_amdgcn_exp2f(s[11]); \
  float pd = __builtin_amdgcn_exp2f(s[12]), pe_ = __builtin_amdgcn_exp2f(s[13]); \
  float pf = __builtin_amdgcn_exp2f(s[14]), pg = __builtin_amdgcn_exp2f(s[15]); \
  LS += (((p0 + p1) + (p2 + p3)) + ((p4 + p5) + (p6 + p7))) + \
        (((p8 + p9) + (pa + pc)) + ((pd + pe_) + (pf + pg))); \
  unsigned x0_ = cvtpk(p0, p1), x1_ = cvtpk(p2, p3); \
  unsigned y0_ = cvtpk(p4, p5), y1_ = cvtpk(p6, p7); \
  P32SWAP(x0_, y0_); P32SWAP(x1_, y1_); \
  unsigned x2_ = cvtpk(p8, p9), x3_ = cvtpk(pa, pc); \
  unsigned y2_ = cvtpk(pd, pe_), y3_ = cvtpk(pf, pg); \
  P32SWAP(x2_, y2_); P32SWAP(x3_, y3_); \
  union { unsigned u[4]; bf16x8 v; } fa_, fb_; \
  fa_.u[0] = x0_; fa_.u[1] = x1_; fa_.u[2] = y0_; fa_.u[3] = y1_; \
  fb_.u[0] = x2_; fb_.u[1] = x3_; fb_.u[2] = y2_; fb_.u[3] = y3_; \
  O = MFMA32(VB0_, fa_.v, O); \
  O = MFMA32(VB1_, fb_.v, O); \
} while (0)

__global__ __launch_bounds__(256) void k_attn_split(const unsigned short* __restrict__ qbf,
                                                    const unsigned short* __restrict__ kpk,
                                                    const unsigned short* __restrict__ vpk,
                                                    unsigned short* __restrict__ po,
                                                    float* __restrict__ pl) {
  int hh = blockIdx.y;
  int sp = blockIdx.z;
  int t = threadIdx.x;
  int wid = t >> 6, l = t & 63;
  int qc = l & 31, hi = l >> 5;
  int l8 = l * 8;
  int q0w = blockIdx.x * 128 + wid * 32;

  const f32x16 zz16 = {0.f};

  const unsigned short* qp = qbf + (size_t)(q0w + qc) * D + hh * 32 + hi * 8;
  bf16x8 qa0 = *(const bf16x8*)(qp);
  bf16x8 qa1 = *(const bf16x8*)(qp + 16);

  const unsigned short* kB = kpk + ((size_t)hh * NT_TOT + sp * (KV_PER / 32)) * 1024;
  const unsigned short* vB = vpk + ((size_t)hh * NT_TOT + sp * (KV_PER / 32)) * 1024;

  f32x16 oA = {0.f}, oB = {0.f};
  float lsA = 0.f, lsB = 0.f;

  bf16x8 ka0, ka1, va0, va1, kb0r, kb1r, vb0r, vb1r;
  ALOAD(ka0, ka1, va0, va1, 0);
  const int NT = KV_PER / 32;  // 24 tiles
  for (int it = 0; it < NT; it += 2) {
    ALOAD(kb0r, kb1r, vb0r, vb1r, it + 1);
    TILE32(ka0, ka1, va0, va1, oA, lsA);
    if (it + 2 < NT) ALOAD(ka0, ka1, va0, va1, it + 2);
    TILE32(kb0r, kb1r, vb0r, vb1r, oB, lsB);
  }

  f32x16 o = oA + oB;
  float lsum = lsA + lsB;
  float lt = lsum + __shfl_xor(lsum, 32, 64);
  size_t pbase = (size_t)(sp * H + hh) * N_NODES + q0w + qc;
  unsigned short* pop = po + pbase * 32 + 4 * hi;
  uint2 v0, v1, v2, v3;
  v0.x = cvtpk(o[0], o[1]);   v0.y = cvtpk(o[2], o[3]);
  v1.x = cvtpk(o[4], o[5]);   v1.y = cvtpk(o[6], o[7]);
  v2.x = cvtpk(o[8], o[9]);   v2.y = cvtpk(o[10], o[11]);
  v3.x = cvtpk(o[12], o[13]); v3.y = cvtpk(o[14], o[15]);
  *(uint2*)(pop)      = v0;
  *(uint2*)(pop + 8)  = v1;
  *(uint2*)(pop + 16) = v2;
  *(uint2*)(pop + 24) = v3;
  if (l < 32) {
    pl[pbase] = lt;
  }
}

__global__ __launch_bounds__(256) void k_attn_combine(const unsigned short* __restrict__ po,
                                                      const float* __restrict__ pl,
                                                      unsigned short* __restrict__ xabf) {
  int t = blockIdx.x * 256 + threadIdx.x;  // N*D/2 threads, 2 chans each
  int q = t >> 6, cp = t & 63;
  int c2 = cp * 2, hh = c2 >> 5, c = c2 & 31;
  int base = hh * N_NODES + q;
  const int SN = H * N_NODES;
  float ll = 0.f, olo = 0.f, ohi = 0.f;
#pragma unroll
  for (int s = 0; s < SPLITS; s++) {
    ll += pl[s * SN + base];
    unsigned dw = *(const unsigned*)(po + ((size_t)(s * SN + base)) * 32 + c);
    olo += bf2f((unsigned short)(dw & 0xffff));
    ohi += bf2f((unsigned short)(dw >> 16));
  }
  float inv = 1.f / ll;
  *(unsigned*)(xabf + (size_t)q * D + c2) = cvtpk(olo * inv, ohi * inv);
}

// ---------- Wo GEMM via MFMA ----------
__global__ __launch_bounds__(256) void k_ca_gemm(const unsigned short* __restrict__ xabf,
                                                 const unsigned short* __restrict__ wot,
                                                 const float* __restrict__ bo,
                                                 float* __restrict__ yb) {
  int t = threadIdx.x;
  int w = t >> 6, l = t & 63, qc = l & 31, hi = l >> 5;
  int row0 = blockIdx.x * 32, col0 = w * 32;
  f32x16 o = tile_gemm128(xabf, wot, row0, col0, qc, hi);
  float bias = bo[col0 + qc];
#pragma unroll
  for (int r = 0; r < 16; r++) {
    int rr = (r & 3) + 8 * (r >> 2) + 4 * hi;
    yb[(size_t)(row0 + rr) * D + col0 + qc] = o[r] + bias;
  }
}

// ---------- residual + LN + pooled + outputs ----------
__global__ __launch_bounds__(128) void k_ca_ln(const float* __restrict__ yb,
                                               const float* __restrict__ g,
                                               const float* __restrict__ bb,
                                               float* __restrict__ x,
                                               unsigned short* __restrict__ xbf,
                                               float* __restrict__ pooled,
                                               float* __restrict__ outx) {
  int tid = threadIdx.x, r0 = blockIdx.x * 8;
  __shared__ float tmp4[4];
  float gv = g[tid], bv = bb[tid];
  float psum = 0.f;
#pragma unroll
  for (int r = 0; r < 8; r++) {
    int n = r0 + r;
    float y = x[n * D + tid] + yb[n * D + tid];
    float s1 = y, s2 = y * y;
    red128_sum2(s1, s2, tmp4, tid);
    float mean = s1 * (1.f / D);
    float var = s2 * (1.f / D) - mean * mean;
    float o = (y - mean) * rsqrtf(var + 1e-5f) * gv + bv;
    x[n * D + tid] = o;
    xbf[n * D + tid] = f2bf(o);
    outx[n * D + tid] = o;
    psum += o;
  }
  atomicAdd(&pooled[tid], psum);
}

// ---------- policy head: stage1/stage2 MFMA, stage3 wave-reduce ----------
__global__ __launch_bounds__(256) void k_policy1(const unsigned short* __restrict__ xbf,
                                                 const unsigned short* __restrict__ w1t,
                                                 const float* __restrict__ b1,
                                                 unsigned short* __restrict__ h1) {
  int t = threadIdx.x;
  int w = t >> 6, l = t & 63, qc = l & 31, hi = l >> 5;
  int row0 = blockIdx.x * 32, col0 = w * 32;
  f32x16 o = tile_gemm128(xbf, w1t, row0, col0, qc, hi);
  float bias = b1[col0 + qc];
#pragma unroll
  for (int r = 0; r < 16; r++) {
    int rr = (r & 3) + 8 * (r >> 2) + 4 * hi;
    h1[(size_t)(row0 + rr) * D + col0 + qc] = f2bf(fmaxf(o[r] + bias, 0.f));
  }
}

__global__ __launch_bounds__(128) void k_policy2(const unsigned short* __restrict__ h1,
                                                 const unsigned short* __restrict__ w2t,
                                                 const float* __restrict__ b2,
                                                 unsigned short* __restrict__ h2) {
  int t = threadIdx.x;
  int w = t >> 6, l = t & 63, qc = l & 31, hi = l >> 5;
  int row0 = blockIdx.x * 32, col0 = w * 32;
  f32x16 o = tile_gemm128(h1, w2t, row0, col0, qc, hi);
  float bias = b2[col0 + qc];
#pragma unroll
  for (int r = 0; r < 16; r++) {
    int rr = (r & 3) + 8 * (r >> 2) + 4 * hi;
    h2[(size_t)(row0 + rr) * 64 + col0 + qc] = f2bf(fmaxf(o[r] + bias, 0.f));
  }
}

__global__ __launch_bounds__(256) void k_policy3(const unsigned short* __restrict__ h2,
                                                 const float* __restrict__ W3,
                                                 const float* __restrict__ b3,
                                                 float* __restrict__ logits) {
  int t = threadIdx.x;
  int wv = t >> 6, l = t & 63;
  int n = blockIdx.x * 4 + wv;
  float h = bf2f(h2[(size_t)n * 64 + l]);
  float p0 = h * W3[l * 2];
  float p1 = h * W3[l * 2 + 1];
#pragma unroll
  for (int m = 1; m < 64; m <<= 1) { p0 += __shfl_xor(p0, m, 64); p1 += __shfl_xor(p1, m, 64); }
  if (l == 0) {
    logits[n * 2] = p0 + b3[0];
    logits[n * 2 + 1] = p1 + b3[1];
  }
}

// ---------- value head (single block) ----------
__global__ __launch_bounds__(128) void k_value(const float* __restrict__ pooled,
                                               const float* __restrict__ W1,
                                               const float* __restrict__ b1,
                                               const float* __restrict__ W2,
                                               const float* __restrict__ b2,
                                               const float* __restrict__ W3,
                                               const float* __restrict__ b3,
                                               float* __restrict__ val) {
  int tid = threadIdx.x;
  __shared__ float ps[D], v1[D], v2[64];
  ps[tid] = pooled[tid] * (1.f / N_NODES);
  __syncthreads();
  float a = b1[tid];
  for (int kk = 0; kk < D; kk++) a += ps[kk] * W1[kk * D + tid];
  v1[tid] = fmaxf(a, 0.f);
  __syncthreads();
  if (tid < 64) {
    float a2 = b2[tid];
    for (int kk = 0; kk < D; kk++) a2 += v1[kk] * W2[kk * 64 + tid];
    v2[tid] = fmaxf(a2, 0.f);
  }
  __syncthreads();
  float p = (tid < 64) ? v2[tid] * W3[tid] : 0.f;
#pragma unroll
  for (int m = 1; m < 64; m <<= 1) p += __shfl_xor(p, m, 64);
  if (tid == 0) val[0] = p + b3[0];
}

extern "C" void kernel_launch(void* const* d_in, const int* in_sizes, int n_in,
                              void* d_out, int out_size, void* d_ws, size_t ws_size,
                              hipStream_t stream) {
  const float* nf   = (const float*)d_in[0];
  const int*   ei   = (const int*)d_in[1];
  const float* pe   = (const float*)d_in[2];
  const float* embW = (const float*)d_in[3];
  const float* embB = (const float*)d_in[4];
  const float* elng = (const float*)d_in[5];
  const float* elnb = (const float*)d_in[6];
  const float* gatW = (const float*)d_in[7];
  const float* aS   = (const float*)d_in[8];
  const float* aD   = (const float*)d_in[9];
  const float* gatB = (const float*)d_in[10];
  const float* lng  = (const float*)d_in[11];
  const float* lnb  = (const float*)d_in[12];
  const float* Wq   = (const float*)d_in[13];
  const float* Wk   = (const float*)d_in[14];
  const float* Wv   = (const float*)d_in[15];
  const float* Wo   = (const float*)d_in[16];
  const float* bq   = (const float*)d_in[17];
  const float* bk   = (const float*)d_in[18];
  const float* bv   = (const float*)d_in[19];
  const float* bo   = (const float*)d_in[20];
  const float* cag  = (const float*)d_in[21];
  const float* cab  = (const float*)d_in[22];
  const float* pW1  = (const float*)d_in[23];
  const float* pb1  = (const float*)d_in[24];
  const float* pW2  = (const float*)d_in[25];
  const float* pb2  = (const float*)d_in[26];
  const float* pW3  = (const float*)d_in[27];
  const float* pb3  = (const float*)d_in[28];
  const float* vW1  = (const float*)d_in[29];
  const float* vb1  = (const float*)d_in[30];
  const float* vW2  = (const float*)d_in[31];
  const float* vb2  = (const float*)d_in[32];
  const float* vW3  = (const float*)d_in[33];
  const float* vb3  = (const float*)d_in[34];

  // workspace layout
  float* fw = (float*)d_ws;
  float* x      = fw; fw += N_NODES * D;
  float* hbuf   = fw; fw += N_NODES * D;   // bf16 h during GAT; fp32 yb for ca
  float* a_s    = fw; fw += N_NODES * H;
  float* a_d    = fw; fw += N_NODES * H;
  float* pooled = fw; fw += 128;
  float* pl     = fw; fw += SPLITS * H * N_NODES;
  unsigned short* ub = (unsigned short*)fw;
  unsigned short* po   = ub; ub += (size_t)SPLITS * H * N_NODES * 32;
  unsigned short* qbf  = ub; ub += N_NODES * D;   // reused as h1/h2 after attention
  unsigned short* kpk  = ub; ub += N_NODES * D;   // reused as xabf after attention
  unsigned short* vpk  = ub; ub += N_NODES * D;
  unsigned short* xbf  = ub; ub += N_NODES * D;
  unsigned short* pebf = ub; ub += N_NODES * D;
  unsigned short* wtb  = ub; ub += L_LAYERS * D * D;
  unsigned short* wqt  = ub; ub += D * D;
  unsigned short* wkt  = ub; ub += D * D;
  unsigned short* wvt  = ub; ub += D * D;
  unsigned short* w1t  = ub; ub += D * D;
  unsigned short* w2t  = ub; ub += 64 * D;
  unsigned short* wot  = ub; ub += D * D;
  int* ib     = (int*)ub;
  int* cnt    = ib; ib += N_NODES;
  int* cur    = ib; ib += N_NODES;
  int* indptr = ib; ib += N_NODES + 16;
  int* sorted = ib;

  unsigned short* hbf  = (unsigned short*)hbuf;  // bf16 alias during GAT
  float* yb            = hbuf;                   // fp32 alias for ca gemm out
  unsigned short* xabf = kpk;                    // kpk free after attn_split
  unsigned short* h1   = qbf;                    // qbf free after attn_split
  unsigned short* h2   = qbf + (size_t)NQ_ * D;

  float* out    = (float*)d_out;
  float* logits = out;
  float* val    = out + NQ_ * 2;
  float* outx   = out + NQ_ * 2 + 1;

  const int* esrc = ei;
  const int* edst = ei + E_EDGES;

  hipLaunchKernelGGL(k_prep, dim3((PREP_ITEMS + 255) / 256), dim3(256), 0, stream,
                     cnt, cur, pooled, gatW, wtb, Wq, Wk, Wv, pW1, pW2, Wo,
                     wqt, wkt, wvt, w1t, w2t, wot, pe, pebf);
  hipLaunchKernelGGL(k_hist, dim3(512), dim3(256), 0, stream, edst, cnt);
  hipLaunchKernelGGL(k_scan, dim3(1), dim3(256), 0, stream, cnt, indptr);
  hipLaunchKernelGGL(k_scatter, dim3(512), dim3(256), 0, stream, esrc, edst, indptr, cur, sorted);
  hipLaunchKernelGGL(k_embed, dim3(N_NODES), dim3(128), 0, stream, nf, embW, embB, elng, elnb, x, xbf);
  for (int l = 0; l < L_LAYERS; l++) {
    hipLaunchKernelGGL(k_gat_gemm, dim3(N_NODES / 32), dim3(256), 0, stream,
                       xbf, wtb + l * D * D, aS + l * D, aD + l * D, hbf, a_s, a_d);
    hipLaunchKernelGGL(k_gat_agg, dim3(N_NODES), dim3(256), 0, stream,
                       hbf, a_s, a_d, indptr, sorted, gatB + l * D, lng + l * D, lnb + l * D, x, xbf);
  }
  hipLaunchKernelGGL(k_qkv_mfma, dim3(N_NODES / 32, 3), dim3(256), 0, stream,
                     xbf, pebf, wqt, wkt, wvt, bq, bk, bv, qbf, kpk, vpk);
  hipLaunchKernelGGL(k_attn_split, dim3(N_NODES / 128, H, SPLITS), dim3(256), 0, stream,
                     qbf, kpk, vpk, po, pl);
  hipLaunchKernelGGL(k_attn_combine, dim3(N_NODES * D / 512), dim3(256), 0, stream,
                     po, pl, xabf);
  hipLaunchKernelGGL(k_ca_gemm, dim3(N_NODES / 32), dim3(256), 0, stream, xabf, wot, bo, yb);
  hipLaunchKernelGGL(k_ca_ln, dim3(N_NODES / 8), dim3(128), 0, stream,
                     yb, cag, cab, x, xbf, pooled, outx);
  hipLaunchKernelGGL(k_policy1, dim3(NQ_ / 32), dim3(256), 0, stream, xbf, w1t, pb1, h1);
  hipLaunchKernelGGL(k_policy2, dim3(NQ_ / 32), dim3(128), 0, stream, h1, w2t, pb2, h2);
  hipLaunchKernelGGL(k_policy3, dim3(NQ_ / 4), dim3(256), 0, stream, h2, pW3, pb3, logits);
  hipLaunchKernelGGL(k_value, dim3(1), dim3(128), 0, stream,
                     pooled, vW1, vb1, vW2, vb2, vW3, vb3, val);
}

// Round 15
// 263.132 us; speedup vs baseline: 1.0622x; 1.0202x over previous
//
#include <hip/hip_runtime.h>
#include <hip/hip_bf16.h>

#define N_NODES 6144
#define NQ_ 3072
#define D 128
#define H 4
#define C 32
#define F_IN 10
#define L_LAYERS 4
#define E_EDGES 393216
#define E_TOT (E_EDGES + N_NODES)
#define SPLITS 8
#define KV_PER (N_NODES / SPLITS)  // 768 keys per split = 24 tiles of 32
#define NT_TOT (N_NODES / 32)      // 192 tiles total
#define LOG2E 1.4426950408889634f

typedef __attribute__((ext_vector_type(8))) short bf16x8;
typedef __attribute__((ext_vector_type(4))) float f32x4;
typedef __attribute__((ext_vector_type(16))) float f32x16;

__device__ __forceinline__ unsigned short f2bf(float f) {
  unsigned u = __float_as_uint(f);
  unsigned r = (u + 0x7fffu + ((u >> 16) & 1u)) >> 16;
  return (unsigned short)r;
}

__device__ __forceinline__ float bf2f(unsigned short s) {
  return __uint_as_float(((unsigned)s) << 16);
}

__device__ __forceinline__ unsigned cvtpk(float lo, float hi) {
  unsigned r;
  asm volatile("v_cvt_pk_bf16_f32 %0, %1, %2" : "=v"(r) : "v"(lo), "v"(hi));
  return r;
}

// vdst-high(lanes 32-63) <-> src0-low(lanes 0-31)
#define P32SWAP(a, b) asm volatile("v_permlane32_swap_b32 %0, %1" : "+v"(a), "+v"(b))

#define MFMA32(A, B, CIN) __builtin_amdgcn_mfma_f32_32x32x16_bf16(A, B, CIN, 0, 0, 0)

// ---------- helpers ----------
// dual reduction for 128-thread blocks: a and b summed in one interleaved tree
__device__ __forceinline__ void red128_sum2(float& a, float& b, float* tmp4, int tid) {
#pragma unroll
  for (int m = 1; m < 64; m <<= 1) {
    a += __shfl_xor(a, m, 64);
    b += __shfl_xor(b, m, 64);
  }
  __syncthreads();
  if ((tid & 63) == 0) {
    tmp4[(tid >> 6) * 2]     = a;
    tmp4[(tid >> 6) * 2 + 1] = b;
  }
  __syncthreads();
  a = tmp4[0] + tmp4[2];
  b = tmp4[1] + tmp4[3];
}

// 32x32 output tile of A(rows x 128) @ B^T(cols x 128), both bf16 row-major.
// lane holds D[row=(r&3)+8*(r>>2)+4*hi][col=qc]  (verified fragment map)
__device__ __forceinline__ f32x16 tile_gemm128(const unsigned short* __restrict__ A,
                                               const unsigned short* __restrict__ Bt,
                                               int row0, int col0, int qc, int hi) {
  const unsigned short* ap = A + (size_t)(row0 + qc) * 128 + hi * 8;
  const unsigned short* bp = Bt + (size_t)(col0 + qc) * 128 + hi * 8;
  f32x16 o = {0.f};
#pragma unroll
  for (int kk = 0; kk < 8; kk++) {
    bf16x8 a = *(const bf16x8*)(ap + kk * 16);
    bf16x8 b = *(const bf16x8*)(bp + kk * 16);
    o = MFMA32(a, b, o);
  }
  return o;
}

// ---------- fused prep: zero counters/pooled, GAT W^T, qkv/mlp W^T, pe->bf16 ----------
__global__ void k_prep(int* cnt, int* cur, float* pooled,
                       const float* __restrict__ gatW, unsigned short* __restrict__ wt,
                       const float* __restrict__ Wq, const float* __restrict__ Wk,
                       const float* __restrict__ Wv, const float* __restrict__ W1,
                       const float* __restrict__ W2, const float* __restrict__ Wo,
                       unsigned short* __restrict__ wqt, unsigned short* __restrict__ wkt,
                       unsigned short* __restrict__ wvt, unsigned short* __restrict__ w1t,
                       unsigned short* __restrict__ w2t, unsigned short* __restrict__ wot,
                       const float* __restrict__ pe, unsigned short* __restrict__ pebf) {
  int i = blockIdx.x * 256 + threadIdx.x;
  if (i < 6272) {
    if (i < N_NODES) { cnt[i] = 0; cur[i] = 0; }
    else pooled[i - N_NODES] = 0.f;
    return;
  }
  i -= 6272;
  if (i < 65536) {  // GAT W -> W^T bf16 (4 layers)
    int l = i >> 14, rem = i & 16383, j = rem >> 7, k = rem & 127;
    wt[i] = f2bf(gatW[l * 16384 + k * 128 + j]);
    return;
  }
  i -= 65536;
  if (i < 90112) {  // qkv/mlp weights
    if (i < 65536) {
      int m = i >> 14, loc = i & 16383, j = loc >> 7, k = loc & 127;
      const float* src = (m == 0) ? Wq : (m == 1) ? Wk : (m == 2) ? Wv : W1;
      unsigned short* dst = (m == 0) ? wqt : (m == 1) ? wkt : (m == 2) ? wvt : w1t;
      dst[loc] = f2bf(src[k * 128 + j]);
    } else if (i < 73728) {
      int loc = i - 65536, j = loc >> 7, k = loc & 127;  // j<64
      w2t[loc] = f2bf(W2[k * 64 + j]);
    } else {
      int loc = i - 73728, j = loc >> 7, k = loc & 127;
      wot[loc] = f2bf(Wo[k * 128 + j]);
    }
    return;
  }
  i -= 90112;
  if (i < N_NODES * D / 4) {  // pe -> bf16, float4 granules
    float4 v = ((const float4*)pe)[i];
    unsigned lo = (unsigned)f2bf(v.x) | ((unsigned)f2bf(v.y) << 16);
    unsigned hi = (unsigned)f2bf(v.z) | ((unsigned)f2bf(v.w) << 16);
    *(uint2*)(pebf + (size_t)i * 4) = make_uint2(lo, hi);
  }
}
#define PREP_ITEMS (6272 + 65536 + 90112 + N_NODES * D / 4)

// ---------- CSR build ----------
__global__ void k_hist(const int* __restrict__ dst, int* __restrict__ cnt) {
  for (int i = blockIdx.x * blockDim.x + threadIdx.x; i < E_EDGES; i += gridDim.x * blockDim.x)
    atomicAdd(&cnt[dst[i]], 1);
}

__global__ void k_scan(const int* __restrict__ cnt, int* __restrict__ indptr) {
  __shared__ int ps[256];
  int tid = threadIdx.x;
  const int CH = N_NODES / 256;  // 24
  int base = tid * CH;
  int loc[CH];
  int s = 0;
#pragma unroll
  for (int i = 0; i < CH; i++) { loc[i] = cnt[base + i] + 1; s += loc[i]; }  // +1 self loop
  ps[tid] = s;
  __syncthreads();
  for (int off = 1; off < 256; off <<= 1) {
    int v = (tid >= off) ? ps[tid - off] : 0;
    __syncthreads();
    ps[tid] += v;
    __syncthreads();
  }
  int run = (tid == 0) ? 0 : ps[tid - 1];
#pragma unroll
  for (int i = 0; i < CH; i++) { indptr[base + i] = run; run += loc[i]; }
  if (tid == 255) indptr[N_NODES] = run;
}

__global__ void k_scatter(const int* __restrict__ src, const int* __restrict__ dst,
                          const int* __restrict__ indptr, int* __restrict__ cur,
                          int* __restrict__ sorted) {
  for (int i = blockIdx.x * blockDim.x + threadIdx.x; i < E_TOT; i += gridDim.x * blockDim.x) {
    if (i < E_EDGES) {
      int d = dst[i];
      int p = atomicAdd(&cur[d], 1);
      sorted[indptr[d] + p] = src[i];
    } else {
      int n = i - E_EDGES;
      int p = atomicAdd(&cur[n], 1);
      sorted[indptr[n] + p] = n;
    }
  }
}

// ---------- embedding ----------
__global__ __launch_bounds__(128) void k_embed(const float* __restrict__ nf,
                                               const float* __restrict__ W,
                                               const float* __restrict__ b,
                                               const float* __restrict__ g,
                                               const float* __restrict__ bb,
                                               float* __restrict__ x,
                                               unsigned short* __restrict__ xbf) {
  int n = blockIdx.x, j = threadIdx.x;
  __shared__ float f[F_IN];
  __shared__ float tmp4[4];
  if (j < F_IN) f[j] = nf[n * F_IN + j];
  __syncthreads();
  float acc = b[j];
#pragma unroll
  for (int k = 0; k < F_IN; k++) acc += f[k] * W[k * D + j];
  float s1 = acc, s2 = acc * acc;
  red128_sum2(s1, s2, tmp4, j);
  float mean = s1 * (1.f / D);
  float var = s2 * (1.f / D) - mean * mean;
  float y = (acc - mean) * rsqrtf(var + 1e-5f) * g[j] + bb[j];
  y = fmaxf(y, 0.f);
  x[n * D + j] = y;
  xbf[n * D + j] = f2bf(y);
}

// ---------- GAT: H = X@W via MFMA (bf16 in/out) ----------
__global__ __launch_bounds__(256) void k_gat_gemm(const unsigned short* __restrict__ xbf,
                                                  const unsigned short* __restrict__ wt,
                                                  unsigned short* __restrict__ hbf) {
  int t = threadIdx.x;
  int w = t >> 6, l = t & 63, qc = l & 31, hi = l >> 5;
  int tile = blockIdx.x * 4 + w;           // 768 tiles = (N/32)*(D/32)
  int row0 = (tile >> 2) * 32, col0 = (tile & 3) * 32;
  f32x16 o = tile_gemm128(xbf, wt, row0, col0, qc, hi);
#pragma unroll
  for (int r = 0; r < 16; r++) {
    int rr = (r & 3) + 8 * (r >> 2) + 4 * hi;
    hbf[(size_t)(row0 + rr) * D + col0 + qc] = f2bf(o[r]);
  }
}

// ---------- GAT: a_s, a_d from h (pre-scaled by log2e) ----------
__global__ __launch_bounds__(128) void k_gat_attn(const unsigned short* __restrict__ hbf,
                                                  const float* __restrict__ asrc,
                                                  const float* __restrict__ adst,
                                                  float* __restrict__ a_s,
                                                  float* __restrict__ a_d) {
  int t = threadIdx.x;
  int ni = t >> 4, j = t & 15;
  int n = blockIdx.x * 8 + ni;
  bf16x8 hv = *(const bf16x8*)(hbf + (size_t)n * D + j * 8);
  float4 a0 = *(const float4*)(asrc + j * 8);
  float4 a1 = *(const float4*)(asrc + j * 8 + 4);
  float4 d0 = *(const float4*)(adst + j * 8);
  float4 d1 = *(const float4*)(adst + j * 8 + 4);
  float h0 = bf2f(hv[0]), h1 = bf2f(hv[1]), h2 = bf2f(hv[2]), h3 = bf2f(hv[3]);
  float h4 = bf2f(hv[4]), h5 = bf2f(hv[5]), h6 = bf2f(hv[6]), h7 = bf2f(hv[7]);
  float p = h0 * a0.x + h1 * a0.y + h2 * a0.z + h3 * a0.w +
            h4 * a1.x + h5 * a1.y + h6 * a1.z + h7 * a1.w;
  float q = h0 * d0.x + h1 * d0.y + h2 * d0.z + h3 * d0.w +
            h4 * d1.x + h5 * d1.y + h6 * d1.z + h7 * d1.w;
  p += __shfl_xor(p, 1); p += __shfl_xor(p, 2);
  q += __shfl_xor(q, 1); q += __shfl_xor(q, 2);
  if ((j & 3) == 0) {
    int head = j >> 2;
    a_s[n * H + head] = p * LOG2E;
    a_d[n * H + head] = q * LOG2E;
  }
}

__device__ __forceinline__ float leaky(float v) { return v > 0.f ? v : 0.2f * v; }

// ---------- GAT aggregation: block per node, staged ex/src, 8-deep gather batches ----------
__global__ __launch_bounds__(256) void k_gat_agg(const unsigned short* __restrict__ hbf,
                                                 const float* __restrict__ a_s,
                                                 const float* __restrict__ a_d,
                                                 const int* __restrict__ indptr,
                                                 const int* __restrict__ sorted,
                                                 const float* __restrict__ gb,
                                                 const float* __restrict__ g,
                                                 const float* __restrict__ bb,
                                                 float* __restrict__ x,
                                                 unsigned short* __restrict__ xbf) {
  int n = blockIdx.x, tid = threadIdx.x;
  int wv = tid >> 6, l = tid & 63;
  int beg = indptr[n], end = indptr[n + 1];
  __shared__ int s_src[256];
  __shared__ float s_ex[256 * 4];
  __shared__ float2 red2[4][64];
  __shared__ float rtmp[16];
  __shared__ float tmp8[8];
  float4 ad = *(const float4*)&a_d[n * H];
  int hsel = l >> 4;  // head of channels 2l, 2l+1
  const unsigned short* hb = hbf + l * 2;
  float accx = 0.f, accy = 0.f;
  float d0 = 0.f, d1 = 0.f, d2 = 0.f, d3 = 0.f;

  for (int c0 = beg; c0 < end; c0 += 256) {
    __syncthreads();
    int e = c0 + tid;
    if (e < end) {
      int s = sorted[e];
      s_src[tid] = s;
      float4 as = *(const float4*)&a_s[s * H];
      float e0 = exp2f(leaky(as.x + ad.x));
      float e1 = exp2f(leaky(as.y + ad.y));
      float e2 = exp2f(leaky(as.z + ad.z));
      float e3 = exp2f(leaky(as.w + ad.w));
      s_ex[tid * 4 + 0] = e0;
      s_ex[tid * 4 + 1] = e1;
      s_ex[tid * 4 + 2] = e2;
      s_ex[tid * 4 + 3] = e3;
      d0 += e0; d1 += e1; d2 += e2; d3 += e3;
    }
    __syncthreads();
    int nc = min(256, end - c0);
    int i = wv;
    // 8-deep batches: 8 independent gathers in flight per wave
    for (; i + 28 < nc; i += 32) {
      int ss[8];
      float aa[8];
#pragma unroll
      for (int u = 0; u < 8; u++) {
        int idx = i + u * 4;
        ss[u] = s_src[idx];
        aa[u] = s_ex[idx * 4 + hsel];
      }
      unsigned dw[8];
#pragma unroll
      for (int u = 0; u < 8; u++) dw[u] = *(const unsigned*)(hb + (size_t)ss[u] * D);
#pragma unroll
      for (int u = 0; u < 8; u++) {
        accx = fmaf(aa[u], bf2f((unsigned short)(dw[u] & 0xffff)), accx);
        accy = fmaf(aa[u], bf2f((unsigned short)(dw[u] >> 16)), accy);
      }
    }
    for (; i < nc; i += 4) {
      float al = s_ex[i * 4 + hsel];
      int s = s_src[i];
      unsigned dw = *(const unsigned*)(hb + (size_t)s * D);
      accx = fmaf(al, bf2f((unsigned short)(dw & 0xffff)), accx);
      accy = fmaf(al, bf2f((unsigned short)(dw >> 16)), accy);
    }
  }
  red2[wv][l] = make_float2(accx, accy);
  // reduce 4 denominators in one interleaved wave tree
#pragma unroll
  for (int m = 1; m < 64; m <<= 1) {
    d0 += __shfl_xor(d0, m, 64);
    d1 += __shfl_xor(d1, m, 64);
    d2 += __shfl_xor(d2, m, 64);
    d3 += __shfl_xor(d3, m, 64);
  }
  if (l == 0) {
    rtmp[wv * 4 + 0] = d0; rtmp[wv * 4 + 1] = d1;
    rtmp[wv * 4 + 2] = d2; rtmp[wv * 4 + 3] = d3;
  }
  __syncthreads();

  float y = 0.f;
  int c = tid;
  if (tid < 128) {
    const float* rp0 = (const float*)&red2[0][c >> 1];
    const float* rp1 = (const float*)&red2[1][c >> 1];
    const float* rp2 = (const float*)&red2[2][c >> 1];
    const float* rp3 = (const float*)&red2[3][c >> 1];
    int par = c & 1;
    float sum = rp0[par] + rp1[par] + rp2[par] + rp3[par];
    int hd = c >> 5;
    float dd = rtmp[hd] + rtmp[4 + hd] + rtmp[8 + hd] + rtmp[12 + hd];
    float outv = sum * (1.f / (dd + 1e-16f)) + gb[c];
    y = x[n * D + c] + fmaxf(outv, 0.f);
  }
  // dual LN reduction across all 4 waves (y=0 for tid>=128)
  float sy = y, syy = y * y;
#pragma unroll
  for (int m = 1; m < 64; m <<= 1) {
    sy += __shfl_xor(sy, m, 64);
    syy += __shfl_xor(syy, m, 64);
  }
  if (l == 0) { tmp8[wv * 2] = sy; tmp8[wv * 2 + 1] = syy; }
  __syncthreads();
  if (tid < 128) {
    float s1 = tmp8[0] + tmp8[2] + tmp8[4] + tmp8[6];
    float s2 = tmp8[1] + tmp8[3] + tmp8[5] + tmp8[7];
    float mean = s1 * (1.f / D);
    float var = s2 * (1.f / D) - mean * mean;
    float o = (y - mean) * rsqrtf(var + 1e-5f) * g[c] + bb[c];
    x[n * D + c] = o;
    xbf[n * D + c] = f2bf(o);
  }
}

// ---------- q/k/v via MFMA -> q row-major bf16 (scaled); K,V packed fragment order ----------
__global__ __launch_bounds__(256) void k_qkv_mfma(const unsigned short* __restrict__ xbf,
                                                  const unsigned short* __restrict__ pebf,
                                                  const unsigned short* __restrict__ wqt,
                                                  const unsigned short* __restrict__ wkt,
                                                  const unsigned short* __restrict__ wvt,
                                                  const float* __restrict__ bq,
                                                  const float* __restrict__ bk,
                                                  const float* __restrict__ bv,
                                                  unsigned short* __restrict__ qbf,
                                                  unsigned short* __restrict__ kpk,
                                                  unsigned short* __restrict__ vpk) {
  int t = threadIdx.x;
  int w = t >> 6, l = t & 63, qc = l & 31, hi = l >> 5;
  int m = blockIdx.y;
  int row0 = blockIdx.x * 32, col0 = w * 32;
  const unsigned short* A = (m == 0) ? xbf : pebf;
  const unsigned short* Bt = (m == 0) ? wqt : (m == 1) ? wkt : wvt;
  f32x16 o = tile_gemm128(A, Bt, row0, col0, qc, hi);
  int c = col0 + qc;
  int hh = col0 >> 5;
  int kt = row0 >> 5;
  if (m == 0) {
    const float sc = 0.25503491f;  // 1/sqrt(32)*log2e
    float bias = bq[c];
#pragma unroll
    for (int r = 0; r < 16; r++) {
      int rr = (r & 3) + 8 * (r >> 2) + 4 * hi;
      qbf[(size_t)(row0 + rr) * D + c] = f2bf((o[r] + bias) * sc);
    }
  } else if (m == 1) {
    float bias = bk[c];
    int kfrag = (qc >> 4) & 1, khi = (qc >> 3) & 1, kj = qc & 7;
    unsigned short* base = kpk + ((((size_t)hh * NT_TOT + kt) * 2 + kfrag) * 64 + khi * 32) * 8 + kj;
#pragma unroll
    for (int r = 0; r < 16; r++) {
      int rr = (r & 3) + 8 * (r >> 2) + 4 * hi;
      base[rr * 8] = f2bf(o[r] + bias);
    }
  } else {
    float bias = bv[c];
#pragma unroll
    for (int r = 0; r < 16; r++) {
      int rr = (r & 3) + 8 * (r >> 2) + 4 * hi;
      int vfrag = (rr >> 4) & 1, vhi = (rr >> 3) & 1, vj = rr & 7;
      vpk[((((size_t)hh * NT_TOT + kt) * 2 + vfrag) * 64 + vhi * 32 + qc) * 8 + vj] =
          f2bf(o[r] + bias);
    }
  }
}

// ---------- flash attention: swapped-operand 32x32 MFMA, no-max softmax, dual acc ----------
#define ALOAD(KA0, KA1, VB0_, VB1_, TI) do { \
  const unsigned short* kp_ = kB + (size_t)(TI) * 1024 + l8; \
  const unsigned short* vp_ = vB + (size_t)(TI) * 1024 + l8; \
  KA0 = *(const bf16x8*)(kp_); \
  KA1 = *(const bf16x8*)(kp_ + 512); \
  VB0_ = *(const bf16x8*)(vp_); \
  VB1_ = *(const bf16x8*)(vp_ + 512); \
} while (0)

#define TILE32(KA0, KA1, VB0_, VB1_, O, LS) do { \
  f32x16 s = MFMA32(KA0, qa0, zz16); \
  s = MFMA32(KA1, qa1, s); \
  float p0 = __builtin_amdgcn_exp2f(s[0]), p1 = __builtin_amdgcn_exp2f(s[1]); \
  float p2 = __builtin_amdgcn_exp2f(s[2]), p3 = __builtin_amdgcn_exp2f(s[3]); \
  float p4 = __builtin_amdgcn_exp2f(s[4]), p5 = __builtin_amdgcn_exp2f(s[5]); \
  float p6 = __builtin_amdgcn_exp2f(s[6]), p7 = __builtin_amdgcn_exp2f(s[7]); \
  float p8 = __builtin_amdgcn_exp2f(s[8]), p9 = __builtin_amdgcn_exp2f(s[9]); \
  float pa = __builtin_amdgcn_exp2f(s[10]), pc = __builtin_amdgcn_exp2f(s[11]); \
  float pd = __builtin_amdgcn_exp2f(s[12]), pe_ = __builtin_amdgcn_exp2f(s[13]); \
  float pf = __builtin_amdgcn_exp2f(s[14]), pg = __builtin_amdgcn_exp2f(s[15]); \
  LS += (((p0 + p1) + (p2 + p3)) + ((p4 + p5) + (p6 + p7))) + \
        (((p8 + p9) + (pa + pc)) + ((pd + pe_) + (pf + pg))); \
  unsigned x0_ = cvtpk(p0, p1), x1_ = cvtpk(p2, p3); \
  unsigned y0_ = cvtpk(p4, p5), y1_ = cvtpk(p6, p7); \
  P32SWAP(x0_, y0_); P32SWAP(x1_, y1_); \
  unsigned x2_ = cvtpk(p8, p9), x3_ = cvtpk(pa, pc); \
  unsigned y2_ = cvtpk(pd, pe_), y3_ = cvtpk(pf, pg); \
  P32SWAP(x2_, y2_); P32SWAP(x3_, y3_); \
  union { unsigned u[4]; bf16x8 v; } fa_, fb_; \
  fa_.u[0] = x0_; fa_.u[1] = x1_; fa_.u[2] = y0_; fa_.u[3] = y1_; \
  fb_.u[0] = x2_; fb_.u[1] = x3_; fb_.u[2] = y2_; fb_.u[3] = y3_; \
  O = MFMA32(VB0_, fa_.v, O); \
  O = MFMA32(VB1_, fb_.v, O); \
} while (0)

// 1D grid, split-major decode: all blocks of split sp land on XCD (sp % 8)
// under the round-robin wgid->XCD heuristic -> each XCD's K/V working set is
// one split (768 KB, L2-resident) instead of all 8.
__global__ __launch_bounds__(256) void k_attn_split(const unsigned short* __restrict__ qbf,
                                                    const unsigned short* __restrict__ kpk,
                                                    const unsigned short* __restrict__ vpk,
                                                    unsigned short* __restrict__ po,
                                                    float* __restrict__ pl) {
  int b = blockIdx.x;
  int sp = b & 7;
  int hh = (b >> 3) & 3;
  int qt = b >> 5;
  int t = threadIdx.x;
  int wid = t >> 6, l = t & 63;
  int qc = l & 31, hi = l >> 5;
  int l8 = l * 8;
  int q0w = qt * 128 + wid * 32;

  const f32x16 zz16 = {0.f};

  const unsigned short* qp = qbf + (size_t)(q0w + qc) * D + hh * 32 + hi * 8;
  bf16x8 qa0 = *(const bf16x8*)(qp);
  bf16x8 qa1 = *(const bf16x8*)(qp + 16);

  const unsigned short* kB = kpk + ((size_t)hh * NT_TOT + sp * (KV_PER / 32)) * 1024;
  const unsigned short* vB = vpk + ((size_t)hh * NT_TOT + sp * (KV_PER / 32)) * 1024;

  f32x16 oA = {0.f}, oB = {0.f};
  float lsA = 0.f, lsB = 0.f;

  bf16x8 ka0, ka1, va0, va1, kb0r, kb1r, vb0r, vb1r;
  ALOAD(ka0, ka1, va0, va1, 0);
  const int NT = KV_PER / 32;  // 24 tiles
  for (int it = 0; it < NT; it += 2) {
    ALOAD(kb0r, kb1r, vb0r, vb1r, it + 1);
    TILE32(ka0, ka1, va0, va1, oA, lsA);
    if (it + 2 < NT) ALOAD(ka0, ka1, va0, va1, it + 2);
    TILE32(kb0r, kb1r, vb0r, vb1r, oB, lsB);
  }

  f32x16 o = oA + oB;
  float lsum = lsA + lsB;
  float lt = lsum + __shfl_xor(lsum, 32, 64);
  size_t pbase = (size_t)(sp * H + hh) * N_NODES + q0w + qc;
  unsigned short* pop = po + pbase * 32 + 4 * hi;
  uint2 v0, v1, v2, v3;
  v0.x = cvtpk(o[0], o[1]);   v0.y = cvtpk(o[2], o[3]);
  v1.x = cvtpk(o[4], o[5]);   v1.y = cvtpk(o[6], o[7]);
  v2.x = cvtpk(o[8], o[9]);   v2.y = cvtpk(o[10], o[11]);
  v3.x = cvtpk(o[12], o[13]); v3.y = cvtpk(o[14], o[15]);
  *(uint2*)(pop)      = v0;
  *(uint2*)(pop + 8)  = v1;
  *(uint2*)(pop + 16) = v2;
  *(uint2*)(pop + 24) = v3;
  if (l < 32) {
    pl[pbase] = lt;
  }
}

__global__ __launch_bounds__(256) void k_attn_combine(const unsigned short* __restrict__ po,
                                                      const float* __restrict__ pl,
                                                      unsigned short* __restrict__ xabf) {
  int t = blockIdx.x * 256 + threadIdx.x;  // N*D/2 threads, 2 chans each
  int q = t >> 6, cp = t & 63;
  int c2 = cp * 2, hh = c2 >> 5, c = c2 & 31;
  int base = hh * N_NODES + q;
  const int SN = H * N_NODES;
  float ll = 0.f, olo = 0.f, ohi = 0.f;
#pragma unroll
  for (int s = 0; s < SPLITS; s++) {
    ll += pl[s * SN + base];
    unsigned dw = *(const unsigned*)(po + ((size_t)(s * SN + base)) * 32 + c);
    olo += bf2f((unsigned short)(dw & 0xffff));
    ohi += bf2f((unsigned short)(dw >> 16));
  }
  float inv = 1.f / ll;
  *(unsigned*)(xabf + (size_t)q * D + c2) = cvtpk(olo * inv, ohi * inv);
}

// ---------- Wo GEMM via MFMA ----------
__global__ __launch_bounds__(256) void k_ca_gemm(const unsigned short* __restrict__ xabf,
                                                 const unsigned short* __restrict__ wot,
                                                 const float* __restrict__ bo,
                                                 float* __restrict__ yb) {
  int t = threadIdx.x;
  int w = t >> 6, l = t & 63, qc = l & 31, hi = l >> 5;
  int row0 = blockIdx.x * 32, col0 = w * 32;
  f32x16 o = tile_gemm128(xabf, wot, row0, col0, qc, hi);
  float bias = bo[col0 + qc];
#pragma unroll
  for (int r = 0; r < 16; r++) {
    int rr = (r & 3) + 8 * (r >> 2) + 4 * hi;
    yb[(size_t)(row0 + rr) * D + col0 + qc] = o[r] + bias;
  }
}

// ---------- residual + LN + pooled + outputs ----------
__global__ __launch_bounds__(128) void k_ca_ln(const float* __restrict__ yb,
                                               const float* __restrict__ g,
                                               const float* __restrict__ bb,
                                               float* __restrict__ x,
                                               unsigned short* __restrict__ xbf,
                                               float* __restrict__ pooled,
                                               float* __restrict__ outx) {
  int tid = threadIdx.x, r0 = blockIdx.x * 8;
  __shared__ float tmp4[4];
  float gv = g[tid], bv = bb[tid];
  float psum = 0.f;
#pragma unroll
  for (int r = 0; r < 8; r++) {
    int n = r0 + r;
    float y = x[n * D + tid] + yb[n * D + tid];
    float s1 = y, s2 = y * y;
    red128_sum2(s1, s2, tmp4, tid);
    float mean = s1 * (1.f / D);
    float var = s2 * (1.f / D) - mean * mean;
    float o = (y - mean) * rsqrtf(var + 1e-5f) * gv + bv;
    x[n * D + tid] = o;
    xbf[n * D + tid] = f2bf(o);
    outx[n * D + tid] = o;
    psum += o;
  }
  atomicAdd(&pooled[tid], psum);
}

// ---------- policy head: stage1/stage2 MFMA, stage3 wave-reduce ----------
__global__ __launch_bounds__(256) void k_policy1(const unsigned short* __restrict__ xbf,
                                                 const unsigned short* __restrict__ w1t,
                                                 const float* __restrict__ b1,
                                                 unsigned short* __restrict__ h1) {
  int t = threadIdx.x;
  int w = t >> 6, l = t & 63, qc = l & 31, hi = l >> 5;
  int row0 = blockIdx.x * 32, col0 = w * 32;
  f32x16 o = tile_gemm128(xbf, w1t, row0, col0, qc, hi);
  float bias = b1[col0 + qc];
#pragma unroll
  for (int r = 0; r < 16; r++) {
    int rr = (r & 3) + 8 * (r >> 2) + 4 * hi;
    h1[(size_t)(row0 + rr) * D + col0 + qc] = f2bf(fmaxf(o[r] + bias, 0.f));
  }
}

__global__ __launch_bounds__(128) void k_policy2(const unsigned short* __restrict__ h1,
                                                 const unsigned short* __restrict__ w2t,
                                                 const float* __restrict__ b2,
                                                 unsigned short* __restrict__ h2) {
  int t = threadIdx.x;
  int w = t >> 6, l = t & 63, qc = l & 31, hi = l >> 5;
  int row0 = blockIdx.x * 32, col0 = w * 32;
  f32x16 o = tile_gemm128(h1, w2t, row0, col0, qc, hi);
  float bias = b2[col0 + qc];
#pragma unroll
  for (int r = 0; r < 16; r++) {
    int rr = (r & 3) + 8 * (r >> 2) + 4 * hi;
    h2[(size_t)(row0 + rr) * 64 + col0 + qc] = f2bf(fmaxf(o[r] + bias, 0.f));
  }
}

__global__ __launch_bounds__(256) void k_policy3(const unsigned short* __restrict__ h2,
                                                 const float* __restrict__ W3,
                                                 const float* __restrict__ b3,
                                                 float* __restrict__ logits) {
  int t = threadIdx.x;
  int wv = t >> 6, l = t & 63;
  int n = blockIdx.x * 4 + wv;
  float h = bf2f(h2[(size_t)n * 64 + l]);
  float p0 = h * W3[l * 2];
  float p1 = h * W3[l * 2 + 1];
#pragma unroll
  for (int m = 1; m < 64; m <<= 1) { p0 += __shfl_xor(p0, m, 64); p1 += __shfl_xor(p1, m, 64); }
  if (l == 0) {
    logits[n * 2] = p0 + b3[0];
    logits[n * 2 + 1] = p1 + b3[1];
  }
}

// ---------- value head (single block) ----------
__global__ __launch_bounds__(128) void k_value(const float* __restrict__ pooled,
                                               const float* __restrict__ W1,
                                               const float* __restrict__ b1,
                                               const float* __restrict__ W2,
                                               const float* __restrict__ b2,
                                               const float* __restrict__ W3,
                                               const float* __restrict__ b3,
                                               float* __restrict__ val) {
  int tid = threadIdx.x;
  __shared__ float ps[D], v1[D], v2[64];
  ps[tid] = pooled[tid] * (1.f / N_NODES);
  __syncthreads();
  float a = b1[tid];
  for (int kk = 0; kk < D; kk++) a += ps[kk] * W1[kk * D + tid];
  v1[tid] = fmaxf(a, 0.f);
  __syncthreads();
  if (tid < 64) {
    float a2 = b2[tid];
    for (int kk = 0; kk < D; kk++) a2 += v1[kk] * W2[kk * 64 + tid];
    v2[tid] = fmaxf(a2, 0.f);
  }
  __syncthreads();
  float p = (tid < 64) ? v2[tid] * W3[tid] : 0.f;
#pragma unroll
  for (int m = 1; m < 64; m <<= 1) p += __shfl_xor(p, m, 64);
  if (tid == 0) val[0] = p + b3[0];
}

extern "C" void kernel_launch(void* const* d_in, const int* in_sizes, int n_in,
                              void* d_out, int out_size, void* d_ws, size_t ws_size,
                              hipStream_t stream) {
  const float* nf   = (const float*)d_in[0];
  const int*   ei   = (const int*)d_in[1];
  const float* pe   = (const float*)d_in[2];
  const float* embW = (const float*)d_in[3];
  const float* embB = (const float*)d_in[4];
  const float* elng = (const float*)d_in[5];
  const float* elnb = (const float*)d_in[6];
  const float* gatW = (const float*)d_in[7];
  const float* aS   = (const float*)d_in[8];
  const float* aD   = (const float*)d_in[9];
  const float* gatB = (const float*)d_in[10];
  const float* lng  = (const float*)d_in[11];
  const float* lnb  = (const float*)d_in[12];
  const float* Wq   = (const float*)d_in[13];
  const float* Wk   = (const float*)d_in[14];
  const float* Wv   = (const float*)d_in[15];
  const float* Wo   = (const float*)d_in[16];
  const float* bq   = (const float*)d_in[17];
  const float* bk   = (const float*)d_in[18];
  const float* bv   = (const float*)d_in[19];
  const float* bo   = (const float*)d_in[20];
  const float* cag  = (const float*)d_in[21];
  const float* cab  = (const float*)d_in[22];
  const float* pW1  = (const float*)d_in[23];
  const float* pb1  = (const float*)d_in[24];
  const float* pW2  = (const float*)d_in[25];
  const float* pb2  = (const float*)d_in[26];
  const float* pW3  = (const float*)d_in[27];
  const float* pb3  = (const float*)d_in[28];
  const float* vW1  = (const float*)d_in[29];
  const float* vb1  = (const float*)d_in[30];
  const float* vW2  = (const float*)d_in[31];
  const float* vb2  = (const float*)d_in[32];
  const float* vW3  = (const float*)d_in[33];
  const float* vb3  = (const float*)d_in[34];

  // workspace layout
  float* fw = (float*)d_ws;
  float* x      = fw; fw += N_NODES * D;
  float* hbuf   = fw; fw += N_NODES * D;   // bf16 h during GAT; fp32 yb for ca
  float* a_s    = fw; fw += N_NODES * H;
  float* a_d    = fw; fw += N_NODES * H;
  float* pooled = fw; fw += 128;
  float* pl     = fw; fw += SPLITS * H * N_NODES;
  unsigned short* ub = (unsigned short*)fw;
  unsigned short* po   = ub; ub += (size_t)SPLITS * H * N_NODES * 32;
  unsigned short* qbf  = ub; ub += N_NODES * D;   // reused as h1/h2 after attention
  unsigned short* kpk  = ub; ub += N_NODES * D;   // reused as xabf after attention
  unsigned short* vpk  = ub; ub += N_NODES * D;
  unsigned short* xbf  = ub; ub += N_NODES * D;
  unsigned short* pebf = ub; ub += N_NODES * D;
  unsigned short* wtb  = ub; ub += L_LAYERS * D * D;
  unsigned short* wqt  = ub; ub += D * D;
  unsigned short* wkt  = ub; ub += D * D;
  unsigned short* wvt  = ub; ub += D * D;
  unsigned short* w1t  = ub; ub += D * D;
  unsigned short* w2t  = ub; ub += 64 * D;
  unsigned short* wot  = ub; ub += D * D;
  int* ib     = (int*)ub;
  int* cnt    = ib; ib += N_NODES;
  int* cur    = ib; ib += N_NODES;
  int* indptr = ib; ib += N_NODES + 16;
  int* sorted = ib;

  unsigned short* hbf  = (unsigned short*)hbuf;  // bf16 alias during GAT
  float* yb            = hbuf;                   // fp32 alias for ca gemm out
  unsigned short* xabf = kpk;                    // kpk free after attn_split
  unsigned short* h1   = qbf;                    // qbf free after attn_split
  unsigned short* h2   = qbf + (size_t)NQ_ * D;

  float* out    = (float*)d_out;
  float* logits = out;
  float* val    = out + NQ_ * 2;
  float* outx   = out + NQ_ * 2 + 1;

  const int* esrc = ei;
  const int* edst = ei + E_EDGES;

  hipLaunchKernelGGL(k_prep, dim3((PREP_ITEMS + 255) / 256), dim3(256), 0, stream,
                     cnt, cur, pooled, gatW, wtb, Wq, Wk, Wv, pW1, pW2, Wo,
                     wqt, wkt, wvt, w1t, w2t, wot, pe, pebf);
  hipLaunchKernelGGL(k_hist, dim3(512), dim3(256), 0, stream, edst, cnt);
  hipLaunchKernelGGL(k_scan, dim3(1), dim3(256), 0, stream, cnt, indptr);
  hipLaunchKernelGGL(k_scatter, dim3(512), dim3(256), 0, stream, esrc, edst, indptr, cur, sorted);
  hipLaunchKernelGGL(k_embed, dim3(N_NODES), dim3(128), 0, stream, nf, embW, embB, elng, elnb, x, xbf);
  for (int l = 0; l < L_LAYERS; l++) {
    hipLaunchKernelGGL(k_gat_gemm, dim3(N_NODES / 32), dim3(256), 0, stream,
                       xbf, wtb + l * D * D, hbf);
    hipLaunchKernelGGL(k_gat_attn, dim3(N_NODES / 8), dim3(128), 0, stream,
                       hbf, aS + l * D, aD + l * D, a_s, a_d);
    hipLaunchKernelGGL(k_gat_agg, dim3(N_NODES), dim3(256), 0, stream,
                       hbf, a_s, a_d, indptr, sorted, gatB + l * D, lng + l * D, lnb + l * D, x, xbf);
  }
  hipLaunchKernelGGL(k_qkv_mfma, dim3(N_NODES / 32, 3), dim3(256), 0, stream,
                     xbf, pebf, wqt, wkt, wvt, bq, bk, bv, qbf, kpk, vpk);
  hipLaunchKernelGGL(k_attn_split, dim3((N_NODES / 128) * H * SPLITS), dim3(256), 0, stream,
                     qbf, kpk, vpk, po, pl);
  hipLaunchKernelGGL(k_attn_combine, dim3(N_NODES * D / 512), dim3(256), 0, stream,
                     po, pl, xabf);
  hipLaunchKernelGGL(k_ca_gemm, dim3(N_NODES / 32), dim3(256), 0, stream, xabf, wot, bo, yb);
  hipLaunchKernelGGL(k_ca_ln, dim3(N_NODES / 8), dim3(128), 0, stream,
                     yb, cag, cab, x, xbf, pooled, outx);
  hipLaunchKernelGGL(k_policy1, dim3(NQ_ / 32), dim3(256), 0, stream, xbf, w1t, pb1, h1);
  hipLaunchKernelGGL(k_policy2, dim3(NQ_ / 32), dim3(128), 0, stream, h1, w2t, pb2, h2);
  hipLaunchKernelGGL(k_policy3, dim3(NQ_ / 4), dim3(256), 0, stream, h2, pW3, pb3, logits);
  hipLaunchKernelGGL(k_value, dim3(1), dim3(128), 0, stream,
                     pooled, vW1, vb1, vW2, vb2, vW3, vb3, val);
}